// Round 13
// baseline (143.596 us; speedup 1.0000x reference)
//
#include <hip/hip_runtime.h>

typedef unsigned short u16;
typedef unsigned int u32;
typedef __attribute__((ext_vector_type(8))) short bf16x8;
typedef __attribute__((ext_vector_type(4))) float f32x4;

#define B_SZ 4
#define S_SZ 1024
#define D_SZ 1024
#define H_SZ 16
#define E_SZ 64
#define M_SZ (B_SZ * S_SZ)   // 4096

__device__ __forceinline__ u16 f2bf(float f) {
  union { float f; unsigned u; } x; x.f = f;
  unsigned r = (x.u + 0x7FFFu + ((x.u >> 16) & 1u)) >> 16;
  return (u16)r;
}

__device__ __forceinline__ u32 pack_bf16(float lo, float hi) {
  return (u32)f2bf(lo) | ((u32)f2bf(hi) << 16);
}

__device__ __forceinline__ void async16(const void* g, void* l) {
  __builtin_amdgcn_global_load_lds(
      (const __attribute__((address_space(1))) void*)g,
      (__attribute__((address_space(3))) void*)l, 16, 0, 0);
}

__device__ __forceinline__ f32x4 mfma16(bf16x8 a, bf16x8 b, f32x4 c) {
  return __builtin_amdgcn_mfma_f32_16x16x32_bf16(a, b, c, 0, 0, 0);
}

// read a bf16x8 fragment from an f32 LDS tile (rows 256B, swizzle ((r&7)<<4))
__device__ __forceinline__ bf16x8 frag_from_f32(const char* lds, int r, int cbytes) {
  int y0 = (r << 8) + (cbytes ^ ((r & 7) << 4));
  f32x4 v0 = *(const f32x4*)(lds + y0);
  f32x4 v1 = *(const f32x4*)(lds + (y0 ^ 16));
  union { u32 u[4]; bf16x8 v; } cv;
  cv.u[0] = pack_bf16(v0[0], v0[1]);
  cv.u[1] = pack_bf16(v0[2], v0[3]);
  cv.u[2] = pack_bf16(v1[0], v1[1]);
  cv.u[3] = pack_bf16(v1[2], v1[3]);
  return cv.v;
}

// ------------- W [H,D,E] f32 -> WT [H*E, D] bf16 for Wq,Wk,Wv -------------
__global__ void transW3(const float* __restrict__ Wq, const float* __restrict__ Wk,
                        const float* __restrict__ Wv, u16* __restrict__ Tq,
                        u16* __restrict__ Tk, u16* __restrict__ Tv) {
  __shared__ float tile[64 * 68];
  const int wsel = blockIdx.x >> 8;
  const int bi = blockIdx.x & 255;
  const float* W = wsel == 0 ? Wq : (wsel == 1 ? Wk : Wv);
  u16* WT = wsel == 0 ? Tq : (wsel == 1 ? Tk : Tv);
  const int tid = threadIdx.x;
  const int h = bi >> 4;
  const int d0 = (bi & 15) << 6;
#pragma unroll
  for (int c = 0; c < 4; ++c) {
    const int dd = c * 16 + (tid >> 4);
    const int e4 = (tid & 15) << 2;
    float4 vq = *(const float4*)(W + (h << 16) + ((d0 + dd) << 6) + e4);
    *(float4*)(tile + dd * 68 + e4) = vq;
  }
  __syncthreads();
  {
    const int e = tid >> 2;
    const int dc = (tid & 3) << 4;
    alignas(16) u16 outv[16];
#pragma unroll
    for (int i = 0; i < 16; ++i) outv[i] = f2bf(tile[(dc + i) * 68 + e]);
    u16* dst = WT + (((size_t)(h << 6) + e) << 10) + d0 + dc;
    *(uint4*)(dst) = *(uint4*)outv;
    *(uint4*)(dst + 8) = *(uint4*)(outv + 8);
  }
}

// ---------------- fused QKV projection GEMM: A staged as f32, cast at frag-read ----------------
// 128x128 tile, BK=64, 4 waves, single-buffered (R10-proven skeleton), T1 swizzle.
// A LDS: f32 [128][64] (32KB, swizzle bits 4-6 ^ row&7); B LDS: bf16 (16KB, old swizzle).
__global__ __launch_bounds__(256)
void gemm3(const float* __restrict__ qf, const float* __restrict__ kf,
           const float* __restrict__ vf,
           const u16* __restrict__ Tq, const u16* __restrict__ Tk, const u16* __restrict__ Tv,
           const float* __restrict__ bq, const float* __restrict__ bk, const float* __restrict__ bv,
           u16* __restrict__ Qp, u16* __restrict__ Kp, u16* __restrict__ VpT) {
  __shared__ float Alf[128 * 64];   // 32KB
  __shared__ u16 Bl[128 * 64];      // 16KB
  const int wg = blockIdx.x;
  const int swz = (wg & 7) * 96 + (wg >> 3);   // T1: bijective (768 % 8 == 0)
  const int g = swz >> 8;
  const int bi = swz & 255;
  const float* A32 = g == 0 ? qf : (g == 1 ? kf : vf);
  const u16* BT = g == 0 ? Tq : (g == 1 ? Tk : Tv);
  const float* bias = g == 0 ? bq : (g == 1 ? bk : bv);
  u16* Cout = g == 0 ? Qp : (g == 1 ? Kp : VpT);
  const float scale = g == 0 ? 0.125f : 1.0f;

  const int tid = threadIdx.x;
  const int wave = tid >> 6;
  const int lane = tid & 63;
  const int l15 = lane & 15, lq = lane >> 4;
  const int bm = bi >> 3;
  const int bn = bi & 7;
  const int row0 = bm << 7, col0 = bn << 7;
  const int wr = ((wave >> 1) & 1) << 6;
  const int wc = (wave & 1) << 6;

  // staging geometry. A (f32): 8 chunks of 16B; dest linear x, source g = x ^ ((rowbits)<<4)
  int xa[8];
  const float* Asrc[8];
#pragma unroll
  for (int c = 0; c < 8; ++c) {
    int x = c * 4096 + tid * 16;
    int gx = x ^ (((x >> 8) & 7) << 4);
    xa[c] = x;
    Asrc[c] = A32 + (size_t)(row0 + (gx >> 8)) * 1024 + ((gx & 255) >> 2);
  }
  // B (bf16): 4 chunks (rows 128B, old swizzle)
  int xb[4];
  const u16* Bsrc[4];
#pragma unroll
  for (int c = 0; c < 4; ++c) {
    int x = c * 4096 + tid * 16;
    int gx = x ^ (((x >> 7) & 7) << 4);
    xb[c] = x;
    Bsrc[c] = BT + (size_t)(col0 + (gx >> 7)) * 1024 + ((gx & 127) >> 1);
  }

  f32x4 acc[4][4];
#pragma unroll
  for (int m = 0; m < 4; ++m)
#pragma unroll
    for (int n = 0; n < 4; ++n) acc[m][n] = (f32x4)0.0f;

  for (int k0 = 0; k0 < 1024; k0 += 64) {
    __syncthreads();
#pragma unroll
    for (int c = 0; c < 8; ++c) async16(Asrc[c] + k0, (char*)Alf + xa[c]);
#pragma unroll
    for (int c = 0; c < 4; ++c) async16(Bsrc[c] + k0, (char*)Bl + xb[c]);
    __syncthreads();

    bf16x8 af[4][2], bfr[4][2];
#pragma unroll
    for (int m = 0; m < 4; ++m)
#pragma unroll
      for (int kk = 0; kk < 2; ++kk)
        af[m][kk] = frag_from_f32((const char*)Alf, wr + m * 16 + l15,
                                  kk * 128 + lq * 32);
#pragma unroll
    for (int n = 0; n < 4; ++n)
#pragma unroll
      for (int kk = 0; kk < 2; ++kk) {
        int r = wc + n * 16 + l15;
        int byte = ((r << 7) + kk * 64 + lq * 16) ^ ((r & 7) << 4);
        bfr[n][kk] = *(const bf16x8*)((const char*)Bl + byte);
      }
    if (g == 2) {
#pragma unroll
      for (int kk = 0; kk < 2; ++kk)
#pragma unroll
        for (int m = 0; m < 4; ++m)
#pragma unroll
          for (int n = 0; n < 4; ++n)
            acc[m][n] = mfma16(af[m][kk], bfr[n][kk], acc[m][n]);
    } else {
#pragma unroll
      for (int kk = 0; kk < 2; ++kk)
#pragma unroll
        for (int m = 0; m < 4; ++m)
#pragma unroll
          for (int n = 0; n < 4; ++n)
            acc[m][n] = mfma16(bfr[n][kk], af[m][kk], acc[m][n]);
    }
  }

  if (g == 2) {
#pragma unroll
    for (int m = 0; m < 4; ++m)
#pragma unroll
      for (int n = 0; n < 4; ++n) {
        int col = col0 + wc + n * 16 + l15;
        float bv = bias[col];
        int rowb = row0 + wr + m * 16 + lq * 4;
        alignas(8) u16 r4[4];
#pragma unroll
        for (int j = 0; j < 4; ++j) r4[j] = f2bf(acc[m][n][j] + bv);
        *(uint2*)(Cout + (size_t)col * 4096 + rowb) = *(uint2*)r4;
      }
  } else {
    float4 b4[4];
#pragma unroll
    for (int n = 0; n < 4; ++n)
      b4[n] = *(const float4*)(bias + col0 + wc + n * 16 + lq * 4);
#pragma unroll
    for (int m = 0; m < 4; ++m) {
      int row = row0 + wr + m * 16 + l15;
#pragma unroll
      for (int n = 0; n < 4; ++n) {
        int colbase = col0 + wc + n * 16 + lq * 4;
        u32 lo = pack_bf16((acc[m][n][0] + b4[n].x) * scale,
                           (acc[m][n][1] + b4[n].y) * scale);
        u32 hi = pack_bf16((acc[m][n][2] + b4[n].z) * scale,
                           (acc[m][n][3] + b4[n].w) * scale);
        uint2 wv; wv.x = lo; wv.y = hi;
        *(uint2*)(Cout + (size_t)row * 1024 + colbase) = wv;
      }
    }
  }
}

// ---------------- output GEMM: 8 waves, dbuf, B (Wo) staged as f32 ----------------
__global__ __launch_bounds__(512, 4)
void gemmO8(const u16* __restrict__ A, const float* __restrict__ Wo32,
            const float* __restrict__ bias, float* __restrict__ out) {
  __shared__ u16 Al[2][128 * 64];     // 2x16KB
  __shared__ float Blf[2][128 * 64];  // 2x32KB  (total 96KB, 1 block/CU as before)
  const int tid = threadIdx.x;
  const int wave = tid >> 6;
  const int lane = tid & 63;
  const int l15 = lane & 15, lq = lane >> 4;
  const int wg = blockIdx.x;
  const int bi = (wg & 7) * 32 + (wg >> 3);   // T1: bijective (256 % 8 == 0)
  const int bm = bi >> 3;
  const int bn = bi & 7;
  const int row0 = bm << 7, col0 = bn << 7;
  const int wr = (wave >> 1) << 5;
  const int wc = (wave & 1) << 6;

  // A (bf16): 2 chunks; B (f32): 4 chunks
  int xa[2];
  const u16* Asrc[2];
#pragma unroll
  for (int c = 0; c < 2; ++c) {
    int x = c * 8192 + tid * 16;
    int gx = x ^ (((x >> 7) & 7) << 4);
    xa[c] = x;
    Asrc[c] = A + (size_t)(row0 + (gx >> 7)) * 1024 + ((gx & 127) >> 1);
  }
  int xbv[4];
  const float* Bsrc[4];
#pragma unroll
  for (int c = 0; c < 4; ++c) {
    int x = c * 8192 + tid * 16;
    int gx = x ^ (((x >> 8) & 7) << 4);
    xbv[c] = x;
    Bsrc[c] = Wo32 + (size_t)(col0 + (gx >> 8)) * 1024 + ((gx & 255) >> 2);
  }

  f32x4 acc[2][4];
#pragma unroll
  for (int m = 0; m < 2; ++m)
#pragma unroll
    for (int n = 0; n < 4; ++n) acc[m][n] = (f32x4)0.0f;

#pragma unroll
  for (int c = 0; c < 2; ++c) async16(Asrc[c], (char*)Al[0] + xa[c]);
#pragma unroll
  for (int c = 0; c < 4; ++c) async16(Bsrc[c], (char*)Blf[0] + xbv[c]);
  __syncthreads();

  int buf = 0;
  for (int k0 = 0; k0 < 1024; k0 += 64) {
    if (k0 + 64 < 1024) {
      const int kn = k0 + 64;
#pragma unroll
      for (int c = 0; c < 2; ++c) async16(Asrc[c] + kn, (char*)Al[buf ^ 1] + xa[c]);
#pragma unroll
      for (int c = 0; c < 4; ++c) async16(Bsrc[c] + kn, (char*)Blf[buf ^ 1] + xbv[c]);
    }

    bf16x8 af[2][2], bfr[4][2];
#pragma unroll
    for (int m = 0; m < 2; ++m)
#pragma unroll
      for (int kk = 0; kk < 2; ++kk) {
        int r = wr + m * 16 + l15;
        int byte = ((r << 7) + kk * 64 + lq * 16) ^ ((r & 7) << 4);
        af[m][kk] = *(const bf16x8*)((const char*)Al[buf] + byte);
      }
#pragma unroll
    for (int n = 0; n < 4; ++n)
#pragma unroll
      for (int kk = 0; kk < 2; ++kk)
        bfr[n][kk] = frag_from_f32((const char*)Blf[buf], wc + n * 16 + l15,
                                   kk * 128 + lq * 32);
#pragma unroll
    for (int kk = 0; kk < 2; ++kk)
#pragma unroll
      for (int m = 0; m < 2; ++m)
#pragma unroll
        for (int n = 0; n < 4; ++n)
          acc[m][n] = mfma16(bfr[n][kk], af[m][kk], acc[m][n]);

    __syncthreads();
    buf ^= 1;
  }

  float4 b4[4];
#pragma unroll
  for (int n = 0; n < 4; ++n)
    b4[n] = *(const float4*)(bias + col0 + wc + n * 16 + lq * 4);
#pragma unroll
  for (int m = 0; m < 2; ++m) {
    int row = row0 + wr + m * 16 + l15;
#pragma unroll
    for (int n = 0; n < 4; ++n) {
      int colbase = col0 + wc + n * 16 + lq * 4;
      float4 v;
      v.x = acc[m][n][0] + b4[n].x;
      v.y = acc[m][n][1] + b4[n].y;
      v.z = acc[m][n][2] + b4[n].z;
      v.w = acc[m][n][3] + b4[n].w;
      *(float4*)(out + (size_t)row * 1024 + colbase) = v;
    }
  }
}

// ---------------- flash attention v4 (R10/R12 proven form) ----------------
__global__ __launch_bounds__(256)
void attn(const u16* __restrict__ Qp, const u16* __restrict__ Kp,
          const u16* __restrict__ VpT, u16* __restrict__ Ow) {
  __shared__ alignas(16) u16 Kl[2][64 * 64];
  __shared__ alignas(16) u16 VTl[2][64 * 64];
  __shared__ alignas(16) u16 Pl[4][2][16 * 64];
  const int tid = threadIdx.x;
  const int wave = tid >> 6;
  const int lane = tid & 63;
  const int l15 = lane & 15, lq = lane >> 4;
  const int wg = blockIdx.x;
  const int swz = (wg & 7) * 64 + (wg >> 3);  // T1: XCD k owns bh in [8k, 8k+8)
  const int qt = swz & 7;
  const int bh = swz >> 3;
  const int b = bh >> 4, h = bh & 15;
  const size_t bS = (size_t)b * S_SZ;

  const int xs0 = tid * 16, xs1 = 4096 + tid * 16;
  const int r0 = xs0 >> 7, r1 = xs1 >> 7;
  const int c0 = ((xs0 & 127) ^ (((xs0 >> 7) & 7) << 4)) >> 1;
  const int c1 = ((xs1 & 127) ^ (((xs1 >> 7) & 7) << 4)) >> 1;
  const u16* Kb0 = Kp + ((bS + r0) << 10) + h * 64 + c0;
  const u16* Kb1 = Kp + ((bS + r1) << 10) + h * 64 + c1;
  const u16* Vb0 = VpT + (size_t)(h * 64 + r0) * 4096 + bS + c0;
  const u16* Vb1 = VpT + (size_t)(h * 64 + r1) * 4096 + bS + c1;

  bf16x8 aq0[2], aq1[2];
  {
    const u16* qp0 = Qp + ((bS + qt * 128 + wave * 32 + l15) << 10) + h * 64 + lq * 8;
    aq0[0] = *(const bf16x8*)(qp0);
    aq0[1] = *(const bf16x8*)(qp0 + 32);
    const u16* qp1 = qp0 + (16 << 10);
    aq1[0] = *(const bf16x8*)(qp1);
    aq1[1] = *(const bf16x8*)(qp1 + 32);
  }

  f32x4 o0[4], o1[4];
#pragma unroll
  for (int n = 0; n < 4; ++n) { o0[n] = (f32x4)0.0f; o1[n] = (f32x4)0.0f; }
  float m0 = -1e30f, m1 = -1e30f;
  float l0 = 0.f, l1 = 0.f;
  u16* Pw0 = Pl[wave][0];
  u16* Pw1 = Pl[wave][1];

  async16(Kb0, (char*)Kl[0] + xs0);
  async16(Kb1, (char*)Kl[0] + xs1);
  async16(Vb0, (char*)VTl[0] + xs0);
  async16(Vb1, (char*)VTl[0] + xs1);
  __syncthreads();

  int buf = 0;
  for (int t0 = 0; t0 < S_SZ; t0 += 64) {
    if (t0 + 64 < S_SZ) {
      const int tn = t0 + 64;
      async16(Kb0 + ((size_t)tn << 10), (char*)Kl[buf ^ 1] + xs0);
      async16(Kb1 + ((size_t)tn << 10), (char*)Kl[buf ^ 1] + xs1);
      async16(Vb0 + tn, (char*)VTl[buf ^ 1] + xs0);
      async16(Vb1 + tn, (char*)VTl[buf ^ 1] + xs1);
    }

    f32x4 s0[4], s1[4];
#pragma unroll
    for (int n = 0; n < 4; ++n) { s0[n] = (f32x4)0.0f; s1[n] = (f32x4)0.0f; }
    __builtin_amdgcn_s_setprio(1);
#pragma unroll
    for (int n = 0; n < 4; ++n)
#pragma unroll
      for (int kk = 0; kk < 2; ++kk) {
        int r = n * 16 + l15;
        int byte = ((r << 7) + kk * 64 + lq * 16) ^ ((r & 7) << 4);
        bf16x8 bk = *(const bf16x8*)((const char*)Kl[buf] + byte);
        s0[n] = mfma16(bk, aq0[kk], s0[n]);
        s1[n] = mfma16(bk, aq1[kk], s1[n]);
      }
    __builtin_amdgcn_s_setprio(0);

    {
      float mx = s0[0][0];
#pragma unroll
      for (int n = 0; n < 4; ++n)
#pragma unroll
        for (int j = 0; j < 4; ++j) mx = fmaxf(mx, s0[n][j]);
      mx = fmaxf(mx, __shfl_xor(mx, 16, 64));
      mx = fmaxf(mx, __shfl_xor(mx, 32, 64));
      if (__any(mx > m0 + 8.0f)) {
        float mn = fmaxf(m0, mx);
        float alpha = __expf(m0 - mn);
        m0 = mn;
        l0 *= alpha;
        float a0 = __shfl(alpha, lq * 4 + 0, 64);
        float a1 = __shfl(alpha, lq * 4 + 1, 64);
        float a2 = __shfl(alpha, lq * 4 + 2, 64);
        float a3 = __shfl(alpha, lq * 4 + 3, 64);
#pragma unroll
        for (int n = 0; n < 4; ++n) {
          o0[n][0] *= a0; o0[n][1] *= a1; o0[n][2] *= a2; o0[n][3] *= a3;
        }
      }
      float rs = 0.f;
#pragma unroll
      for (int n = 0; n < 4; ++n) {
        float p0 = __expf(s0[n][0] - m0);
        float p1 = __expf(s0[n][1] - m0);
        float p2 = __expf(s0[n][2] - m0);
        float p3 = __expf(s0[n][3] - m0);
        rs += (p0 + p1) + (p2 + p3);
        u32 lo = pack_bf16(p0, p1);
        u32 hi = pack_bf16(p2, p3);
        int byte = (l15 << 7) + (((n * 32 + lq * 8)) ^ ((l15 & 7) << 4));
        uint2 wv; wv.x = lo; wv.y = hi;
        *(uint2*)((char*)Pw0 + byte) = wv;
      }
      rs += __shfl_xor(rs, 16, 64);
      rs += __shfl_xor(rs, 32, 64);
      l0 += rs;
    }
    {
      float mx = s1[0][0];
#pragma unroll
      for (int n = 0; n < 4; ++n)
#pragma unroll
        for (int j = 0; j < 4; ++j) mx = fmaxf(mx, s1[n][j]);
      mx = fmaxf(mx, __shfl_xor(mx, 16, 64));
      mx = fmaxf(mx, __shfl_xor(mx, 32, 64));
      if (__any(mx > m1 + 8.0f)) {
        float mn = fmaxf(m1, mx);
        float alpha = __expf(m1 - mn);
        m1 = mn;
        l1 *= alpha;
        float a0 = __shfl(alpha, lq * 4 + 0, 64);
        float a1 = __shfl(alpha, lq * 4 + 1, 64);
        float a2 = __shfl(alpha, lq * 4 + 2, 64);
        float a3 = __shfl(alpha, lq * 4 + 3, 64);
#pragma unroll
        for (int n = 0; n < 4; ++n) {
          o1[n][0] *= a0; o1[n][1] *= a1; o1[n][2] *= a2; o1[n][3] *= a3;
        }
      }
      float rs = 0.f;
#pragma unroll
      for (int n = 0; n < 4; ++n) {
        float p0 = __expf(s1[n][0] - m1);
        float p1 = __expf(s1[n][1] - m1);
        float p2 = __expf(s1[n][2] - m1);
        float p3 = __expf(s1[n][3] - m1);
        rs += (p0 + p1) + (p2 + p3);
        u32 lo = pack_bf16(p0, p1);
        u32 hi = pack_bf16(p2, p3);
        int byte = (l15 << 7) + (((n * 32 + lq * 8)) ^ ((l15 & 7) << 4));
        uint2 wv; wv.x = lo; wv.y = hi;
        *(uint2*)((char*)Pw1 + byte) = wv;
      }
      rs += __shfl_xor(rs, 16, 64);
      rs += __shfl_xor(rs, 32, 64);
      l1 += rs;
    }

    __builtin_amdgcn_s_setprio(1);
#pragma unroll
    for (int kk = 0; kk < 2; ++kk) {
      int pbyte = (l15 << 7) + ((kk * 64 + lq * 16) ^ ((l15 & 7) << 4));
      bf16x8 pa0 = *(const bf16x8*)((const char*)Pw0 + pbyte);
      bf16x8 pa1 = *(const bf16x8*)((const char*)Pw1 + pbyte);
#pragma unroll
      for (int n = 0; n < 4; ++n) {
        int vr = n * 16 + l15;
        int byte = ((vr << 7) + kk * 64 + lq * 16) ^ ((vr & 7) << 4);
        bf16x8 bv = *(const bf16x8*)((const char*)VTl[buf] + byte);
        o0[n] = mfma16(pa0, bv, o0[n]);
        o1[n] = mfma16(pa1, bv, o1[n]);
      }
    }
    __builtin_amdgcn_s_setprio(0);

    __syncthreads();
    buf ^= 1;
  }

#pragma unroll
  for (int qg = 0; qg < 2; ++qg) {
    float lr = qg == 0 ? l0 : l1;
    f32x4* o = qg == 0 ? o0 : o1;
    float li0 = __shfl(lr, lq * 4 + 0, 64);
    float li1 = __shfl(lr, lq * 4 + 1, 64);
    float li2 = __shfl(lr, lq * 4 + 2, 64);
    float li3 = __shfl(lr, lq * 4 + 3, 64);
    float inv0 = 1.0f / li0, inv1 = 1.0f / li1, inv2 = 1.0f / li2, inv3 = 1.0f / li3;
#pragma unroll
    for (int n = 0; n < 4; ++n) {
      float vals[4] = {o[n][0] * inv0, o[n][1] * inv1, o[n][2] * inv2, o[n][3] * inv3};
#pragma unroll
      for (int j = 0; j < 4; ++j) {
        int row = qt * 128 + wave * 32 + qg * 16 + lq * 4 + j;
        int col = h * 64 + n * 16 + l15;
        Ow[((bS + row) << 10) + col] = f2bf(vals[j]);
      }
    }
  }
}

extern "C" void kernel_launch(void* const* d_in, const int* in_sizes, int n_in,
                              void* d_out, int out_size, void* d_ws, size_t ws_size,
                              hipStream_t stream) {
  const float* q  = (const float*)d_in[0];
  const float* k  = (const float*)d_in[1];
  const float* v  = (const float*)d_in[2];
  const float* Wq = (const float*)d_in[3];
  const float* bq = (const float*)d_in[4];
  const float* Wk = (const float*)d_in[5];
  const float* bk = (const float*)d_in[6];
  const float* Wv = (const float*)d_in[7];
  const float* bv = (const float*)d_in[8];
  const float* Wo = (const float*)d_in[9];
  const float* bo = (const float*)d_in[10];

  char* w = (char*)d_ws;
  const size_t MB = 1u << 20;
  u16* WqT = (u16*)(w + 24 * MB);
  u16* WkT = (u16*)(w + 26 * MB);
  u16* WvT = (u16*)(w + 28 * MB);
  u16* Qp  = (u16*)(w + 32 * MB);
  u16* Kp  = (u16*)(w + 40 * MB);
  u16* VpT = (u16*)(w + 48 * MB);
  u16* wvb = (u16*)(w + 56 * MB);

  transW3<<<768, 256, 0, stream>>>(Wq, Wk, Wv, WqT, WkT, WvT);

  gemm3<<<768, 256, 0, stream>>>(q, k, v, WqT, WkT, WvT, bq, bk, bv, Qp, Kp, VpT);

  attn<<<512, 256, 0, stream>>>(Qp, Kp, VpT, wvb);

  gemmO8<<<256, 512, 0, stream>>>(wvb, Wo, bo, (float*)d_out);
}

// Round 14
// 130.794 us; speedup vs baseline: 1.0979x; 1.0979x over previous
//
#include <hip/hip_runtime.h>

typedef unsigned short u16;
typedef unsigned int u32;
typedef __attribute__((ext_vector_type(8))) short bf16x8;
typedef __attribute__((ext_vector_type(4))) float f32x4;

#define B_SZ 4
#define S_SZ 1024
#define D_SZ 1024
#define H_SZ 16
#define E_SZ 64
#define M_SZ (B_SZ * S_SZ)   // 4096
#define NT 16                // K-tiles (1024/64)

__device__ __forceinline__ u16 f2bf(float f) {
  union { float f; unsigned u; } x; x.f = f;
  unsigned r = (x.u + 0x7FFFu + ((x.u >> 16) & 1u)) >> 16;
  return (u16)r;
}

__device__ __forceinline__ u32 pack_bf16(float lo, float hi) {
  return (u32)f2bf(lo) | ((u32)f2bf(hi) << 16);
}

__device__ __forceinline__ void async16(const void* g, void* l) {
  __builtin_amdgcn_global_load_lds(
      (const __attribute__((address_space(1))) void*)g,
      (__attribute__((address_space(3))) void*)l, 16, 0, 0);
}

__device__ __forceinline__ f32x4 mfma16(bf16x8 a, bf16x8 b, f32x4 c) {
  return __builtin_amdgcn_mfma_f32_16x16x32_bf16(a, b, c, 0, 0, 0);
}

#define BARM asm volatile("s_barrier" ::: "memory")
#define VMW4 asm volatile("s_waitcnt vmcnt(4)" ::: "memory")
#define VMW0 asm volatile("s_waitcnt vmcnt(0)" ::: "memory")

// -------- merged prep: blocks [0,6656) cast q,k,v,Wo -> bf16; [6656,7424) transW --------
__global__ void prep(const float* __restrict__ q, const float* __restrict__ k,
                     const float* __restrict__ v, const float* __restrict__ Wo,
                     const float* __restrict__ Wq, const float* __restrict__ Wk,
                     const float* __restrict__ Wv,
                     u16* __restrict__ oq, u16* __restrict__ ok,
                     u16* __restrict__ ov, u16* __restrict__ oWo,
                     u16* __restrict__ Tq, u16* __restrict__ Tk, u16* __restrict__ Tv) {
  __shared__ float tile[64 * 68];
  const int tid = threadIdx.x;
  if (blockIdx.x < 6656) {
    int gid = blockIdx.x * 256 + tid;
    const float* in;
    u16* out;
    int i;
    if (gid < (3 << 19)) {
      int sel = gid >> 19;
      i = (gid & ((1 << 19) - 1)) << 3;
      in = sel == 0 ? q : (sel == 1 ? k : v);
      out = sel == 0 ? oq : (sel == 1 ? ok : ov);
    } else {
      i = (gid - (3 << 19)) << 3;
      in = Wo;
      out = oWo;
    }
    float4 a = *(const float4*)(in + i);
    float4 b = *(const float4*)(in + i + 4);
    alignas(16) u16 r[8];
    r[0] = f2bf(a.x); r[1] = f2bf(a.y); r[2] = f2bf(a.z); r[3] = f2bf(a.w);
    r[4] = f2bf(b.x); r[5] = f2bf(b.y); r[6] = f2bf(b.z); r[7] = f2bf(b.w);
    *(uint4*)(out + i) = *(uint4*)r;
  } else {
    const int blk = blockIdx.x - 6656;
    const int wsel = blk >> 8;
    const int bi = blk & 255;
    const float* W = wsel == 0 ? Wq : (wsel == 1 ? Wk : Wv);
    u16* WT = wsel == 0 ? Tq : (wsel == 1 ? Tk : Tv);
    const int h = bi >> 4;
    const int d0 = (bi & 15) << 6;
#pragma unroll
    for (int c = 0; c < 4; ++c) {
      const int dd = c * 16 + (tid >> 4);
      const int e4 = (tid & 15) << 2;
      float4 vq = *(const float4*)(W + (h << 16) + ((d0 + dd) << 6) + e4);
      *(float4*)(tile + dd * 68 + e4) = vq;
    }
    __syncthreads();
    {
      const int e = tid >> 2;
      const int dc = (tid & 3) << 4;
      alignas(16) u16 outv[16];
#pragma unroll
      for (int i = 0; i < 16; ++i) outv[i] = f2bf(tile[(dc + i) * 68 + e]);
      u16* dst = WT + (((size_t)(h << 6) + e) << 10) + d0 + dc;
      *(uint4*)(dst) = *(uint4*)outv;
      *(uint4*)(dst + 8) = *(uint4*)(outv + 8);
    }
  }
}

// ---------------- fused QKV projection GEMM: 8-phase counted-vmcnt, 256^2 tile ----------------
// 192 blocks x 512 thr (8 waves 2Mx4N). LDS 128KB (2 dbuf x (A 32K + B 32K)).
// Staging: global_load_lds w/ source preswizzle (linear dest), 1 half-tile (2 loads/thr)
// per phase, issue order per tile t: A1_{t+1}@ph0, B1_{t+1}@ph1, B0_{t+2}@ph2, A0_{t+2}@ph3.
// Boundary: vmcnt(4) (retires exactly tile t+1's 8 loads, leaves 4 in flight) + s_barrier.
#define STAGE_T(Ml, Moff, t, h)                                                        \
  do {                                                                                 \
    async16(Moff + ((h) * 128 + 0) * 1024 + (t) * 64,                                  \
            (char*)Ml[(t) & 1] + (h) * 16384 + 0 * 8192 + x0);                         \
    async16(Moff + ((h) * 128 + 64) * 1024 + (t) * 64,                                 \
            (char*)Ml[(t) & 1] + (h) * 16384 + 1 * 8192 + x0);                         \
  } while (0)

__global__ __launch_bounds__(512, 2)
void gemm3(const u16* __restrict__ qb, const u16* __restrict__ kb, const u16* __restrict__ vb,
           const u16* __restrict__ Tq, const u16* __restrict__ Tk, const u16* __restrict__ Tv,
           const float* __restrict__ bq, const float* __restrict__ bk, const float* __restrict__ bv,
           u16* __restrict__ Qp, u16* __restrict__ Kp, u16* __restrict__ VpT) {
  __shared__ u16 Al[2][256 * 64];
  __shared__ u16 Bl[2][256 * 64];
  const int wg = blockIdx.x;
  const int swz = (wg & 7) * 24 + (wg >> 3);   // T1: bijective (192 % 8 == 0)
  const int g = swz >> 6;
  const int bi = swz & 63;
  const u16* A = g == 0 ? qb : (g == 1 ? kb : vb);
  const u16* BT = g == 0 ? Tq : (g == 1 ? Tk : Tv);
  const float* bias = g == 0 ? bq : (g == 1 ? bk : bv);
  u16* Cout = g == 0 ? Qp : (g == 1 ? Kp : VpT);
  const float scale = g == 0 ? 0.125f : 1.0f;

  const int tid = threadIdx.x;
  const int wave = tid >> 6;
  const int lane = tid & 63;
  const int l15 = lane & 15, lq = lane >> 4;
  const int bm = bi >> 2, bn = bi & 3;
  const int row0 = bm << 8, col0 = bn << 8;
  const int wm = wave >> 2, wn = wave & 3;

  // staging geometry: per-thread source (preswizzled), linear LDS dest
  const int x0 = tid * 16;                       // 0..8191
  const int sw = ((x0 >> 7) & 7) << 4;
  const int gx0 = x0 ^ sw;
  const int srow = gx0 >> 7;                     // 0..63
  const int selem = (gx0 & 127) >> 1;
  const u16* Aoff = A + (size_t)(row0 + srow) * 1024 + selem;
  const u16* Boff = BT + (size_t)(col0 + srow) * 1024 + selem;

  f32x4 acc[8][4];
#pragma unroll
  for (int m = 0; m < 8; ++m)
#pragma unroll
    for (int n = 0; n < 4; ++n) acc[m][n] = (f32x4)0.0f;

  // prologue: tile0 all 4 halves + tile1's B0, A0  (12 loads); wait oldest 8; barrier
  STAGE_T(Bl, Boff, 0, 0);
  STAGE_T(Al, Aoff, 0, 0);
  STAGE_T(Al, Aoff, 0, 1);
  STAGE_T(Bl, Boff, 0, 1);
  STAGE_T(Bl, Boff, 1, 0);
  STAGE_T(Al, Aoff, 1, 0);
  VMW4;
  BARM;

  bf16x8 af[4][2], bf[4][2];

#pragma unroll 1
  for (int t = 0; t < NT; ++t) {
    const int b = t & 1;

    // ---- phase 0: (m-half0, n-half0); read af(mh0)+bf(n0); stage A1_{t+1}
#pragma unroll
    for (int i = 0; i < 4; ++i)
#pragma unroll
      for (int kk = 0; kk < 2; ++kk) {
        int r = wm * 128 + i * 16 + l15;
        af[i][kk] = *(const bf16x8*)((const char*)Al[b] +
                     ((r << 7) + ((kk * 64 + lq * 16) ^ ((r & 7) << 4))));
      }
#pragma unroll
    for (int j = 0; j < 2; ++j)
#pragma unroll
      for (int kk = 0; kk < 2; ++kk) {
        int rc = wn * 64 + j * 16 + l15;
        bf[j][kk] = *(const bf16x8*)((const char*)Bl[b] +
                     ((rc << 7) + ((kk * 64 + lq * 16) ^ ((rc & 7) << 4))));
      }
    if (t + 1 < NT) STAGE_T(Al, Aoff, t + 1, 1);
    BARM;
    __builtin_amdgcn_s_setprio(1);
#pragma unroll
    for (int kk = 0; kk < 2; ++kk)
#pragma unroll
      for (int i = 0; i < 4; ++i)
#pragma unroll
        for (int j = 0; j < 2; ++j)
          acc[i][j] = (g == 2) ? mfma16(af[i][kk], bf[j][kk], acc[i][j])
                               : mfma16(bf[j][kk], af[i][kk], acc[i][j]);
    __builtin_amdgcn_s_setprio(0);
    BARM;

    // ---- phase 1: (m0, n1); read bf(n1); stage B1_{t+1}
#pragma unroll
    for (int j = 0; j < 2; ++j)
#pragma unroll
      for (int kk = 0; kk < 2; ++kk) {
        int rc = wn * 64 + (2 + j) * 16 + l15;
        bf[2 + j][kk] = *(const bf16x8*)((const char*)Bl[b] +
                         ((rc << 7) + ((kk * 64 + lq * 16) ^ ((rc & 7) << 4))));
      }
    if (t + 1 < NT) STAGE_T(Bl, Boff, t + 1, 1);
    BARM;
    __builtin_amdgcn_s_setprio(1);
#pragma unroll
    for (int kk = 0; kk < 2; ++kk)
#pragma unroll
      for (int i = 0; i < 4; ++i)
#pragma unroll
        for (int j = 0; j < 2; ++j)
          acc[i][2 + j] = (g == 2) ? mfma16(af[i][kk], bf[2 + j][kk], acc[i][2 + j])
                                   : mfma16(bf[2 + j][kk], af[i][kk], acc[i][2 + j]);
    __builtin_amdgcn_s_setprio(0);
    BARM;

    // ---- phase 2: (m1, n0); read af(mh1); stage B0_{t+2}
#pragma unroll
    for (int i = 0; i < 4; ++i)
#pragma unroll
      for (int kk = 0; kk < 2; ++kk) {
        int r = wm * 128 + (4 + i) * 16 + l15;
        af[i][kk] = *(const bf16x8*)((const char*)Al[b] +
                     ((r << 7) + ((kk * 64 + lq * 16) ^ ((r & 7) << 4))));
      }
    if (t + 2 < NT) STAGE_T(Bl, Boff, t + 2, 0);
    BARM;
    __builtin_amdgcn_s_setprio(1);
#pragma unroll
    for (int kk = 0; kk < 2; ++kk)
#pragma unroll
      for (int i = 0; i < 4; ++i)
#pragma unroll
        for (int j = 0; j < 2; ++j)
          acc[4 + i][j] = (g == 2) ? mfma16(af[i][kk], bf[j][kk], acc[4 + i][j])
                                   : mfma16(bf[j][kk], af[i][kk], acc[4 + i][j]);
    __builtin_amdgcn_s_setprio(0);
    BARM;

    // ---- phase 3: (m1, n1); no reads; stage A0_{t+2}
    if (t + 2 < NT) STAGE_T(Al, Aoff, t + 2, 0);
    BARM;
    __builtin_amdgcn_s_setprio(1);
#pragma unroll
    for (int kk = 0; kk < 2; ++kk)
#pragma unroll
      for (int i = 0; i < 4; ++i)
#pragma unroll
        for (int j = 0; j < 2; ++j)
          acc[4 + i][2 + j] = (g == 2) ? mfma16(af[i][kk], bf[2 + j][kk], acc[4 + i][2 + j])
                                       : mfma16(bf[2 + j][kk], af[i][kk], acc[4 + i][2 + j]);
    __builtin_amdgcn_s_setprio(0);

    // ---- boundary: counted vmcnt (never 0 until epilogue) + barrier
    if (t < NT - 1) {
      if (t < NT - 2) { VMW4; } else { VMW0; }
    }
    BARM;
  }

  // ---------------- epilogue ----------------
  if (g == 2) {
    // unswapped: lane holds col fixed, 4 rows -> VpT [col][row]
#pragma unroll
    for (int m = 0; m < 8; ++m)
#pragma unroll
      for (int n = 0; n < 4; ++n) {
        int col = col0 + wn * 64 + n * 16 + l15;
        float bv = bias[col];
        int rowb = row0 + wm * 128 + m * 16 + lq * 4;
        alignas(8) u16 r4[4];
#pragma unroll
        for (int j = 0; j < 4; ++j) r4[j] = f2bf(acc[m][n][j] + bv);
        *(uint2*)(Cout + (size_t)col * 4096 + rowb) = *(uint2*)r4;
      }
  } else {
    // swapped: lane holds row fixed, 4 consecutive cols
    float4 b4[4];
#pragma unroll
    for (int n = 0; n < 4; ++n)
      b4[n] = *(const float4*)(bias + col0 + wn * 64 + n * 16 + lq * 4);
#pragma unroll
    for (int m = 0; m < 8; ++m) {
      int row = row0 + wm * 128 + m * 16 + l15;
#pragma unroll
      for (int n = 0; n < 4; ++n) {
        int colbase = col0 + wn * 64 + n * 16 + lq * 4;
        u32 lo = pack_bf16((acc[m][n][0] + b4[n].x) * scale,
                           (acc[m][n][1] + b4[n].y) * scale);
        u32 hi = pack_bf16((acc[m][n][2] + b4[n].z) * scale,
                           (acc[m][n][3] + b4[n].w) * scale);
        uint2 wv; wv.x = lo; wv.y = hi;
        *(uint2*)(Cout + (size_t)row * 1024 + colbase) = wv;
      }
    }
  }
}

// ---------------- output GEMM: 8 waves + dbuf prefetch + T1 swizzle (R12 proven) ----------------
__global__ __launch_bounds__(512, 4)
void gemmO8(const u16* __restrict__ A, const u16* __restrict__ BT,
            const float* __restrict__ bias, float* __restrict__ out) {
  __shared__ u16 Al[2][128 * 64];
  __shared__ u16 Bl[2][128 * 64];
  const int tid = threadIdx.x;
  const int wave = tid >> 6;
  const int lane = tid & 63;
  const int l15 = lane & 15, lq = lane >> 4;
  const int wg = blockIdx.x;
  const int bi = (wg & 7) * 32 + (wg >> 3);
  const int bm = bi >> 3;
  const int bn = bi & 7;
  const int row0 = bm << 7, col0 = bn << 7;
  const int wr = (wave >> 1) << 5;
  const int wc = (wave & 1) << 6;

  int xs[2], rowS[2], cbS[2];
#pragma unroll
  for (int c = 0; c < 2; ++c) {
    int x = c * 8192 + tid * 16;
    int gx = x ^ (((x >> 7) & 7) << 4);
    xs[c] = x;
    rowS[c] = gx >> 7;
    cbS[c] = (gx & 127) >> 1;
  }

  f32x4 acc[2][4];
#pragma unroll
  for (int m = 0; m < 2; ++m)
#pragma unroll
    for (int n = 0; n < 4; ++n) acc[m][n] = (f32x4)0.0f;

#pragma unroll
  for (int c = 0; c < 2; ++c) {
    async16(A + (size_t)(row0 + rowS[c]) * 1024 + cbS[c], (char*)Al[0] + xs[c]);
    async16(BT + (size_t)(col0 + rowS[c]) * 1024 + cbS[c], (char*)Bl[0] + xs[c]);
  }
  __syncthreads();

  int buf = 0;
  for (int k0 = 0; k0 < 1024; k0 += 64) {
    if (k0 + 64 < 1024) {
      const int kn = k0 + 64;
#pragma unroll
      for (int c = 0; c < 2; ++c) {
        async16(A + (size_t)(row0 + rowS[c]) * 1024 + kn + cbS[c], (char*)Al[buf ^ 1] + xs[c]);
        async16(BT + (size_t)(col0 + rowS[c]) * 1024 + kn + cbS[c], (char*)Bl[buf ^ 1] + xs[c]);
      }
    }

    bf16x8 af[2][2], bfr[4][2];
#pragma unroll
    for (int m = 0; m < 2; ++m)
#pragma unroll
      for (int kf = 0; kf < 2; ++kf) {
        int r = wr + m * 16 + l15;
        int byte = ((r << 7) + kf * 64 + lq * 16) ^ ((r & 7) << 4);
        af[m][kf] = *(const bf16x8*)((const char*)Al[buf] + byte);
      }
#pragma unroll
    for (int n = 0; n < 4; ++n)
#pragma unroll
      for (int kf = 0; kf < 2; ++kf) {
        int r = wc + n * 16 + l15;
        int byte = ((r << 7) + kf * 64 + lq * 16) ^ ((r & 7) << 4);
        bfr[n][kf] = *(const bf16x8*)((const char*)Bl[buf] + byte);
      }
#pragma unroll
    for (int kf = 0; kf < 2; ++kf)
#pragma unroll
      for (int m = 0; m < 2; ++m)
#pragma unroll
        for (int n = 0; n < 4; ++n)
          acc[m][n] = mfma16(bfr[n][kf], af[m][kf], acc[m][n]);

    __syncthreads();
    buf ^= 1;
  }

  float4 b4[4];
#pragma unroll
  for (int n = 0; n < 4; ++n)
    b4[n] = *(const float4*)(bias + col0 + wc + n * 16 + lq * 4);
#pragma unroll
  for (int m = 0; m < 2; ++m) {
    int row = row0 + wr + m * 16 + l15;
#pragma unroll
    for (int n = 0; n < 4; ++n) {
      int colbase = col0 + wc + n * 16 + lq * 4;
      float4 v;
      v.x = acc[m][n][0] + b4[n].x;
      v.y = acc[m][n][1] + b4[n].y;
      v.z = acc[m][n][2] + b4[n].z;
      v.w = acc[m][n][3] + b4[n].w;
      *(float4*)(out + (size_t)row * 1024 + colbase) = v;
    }
  }
}

// ---------------- flash attention v4 (R12 proven form) ----------------
__global__ __launch_bounds__(256)
void attn(const u16* __restrict__ Qp, const u16* __restrict__ Kp,
          const u16* __restrict__ VpT, u16* __restrict__ Ow) {
  __shared__ alignas(16) u16 Kl[2][64 * 64];
  __shared__ alignas(16) u16 VTl[2][64 * 64];
  __shared__ alignas(16) u16 Pl[4][2][16 * 64];
  const int tid = threadIdx.x;
  const int wave = tid >> 6;
  const int lane = tid & 63;
  const int l15 = lane & 15, lq = lane >> 4;
  const int wg = blockIdx.x;
  const int swz = (wg & 7) * 64 + (wg >> 3);
  const int qt = swz & 7;
  const int bh = swz >> 3;
  const int b = bh >> 4, h = bh & 15;
  const size_t bS = (size_t)b * S_SZ;

  const int xs0 = tid * 16, xs1 = 4096 + tid * 16;
  const int r0 = xs0 >> 7, r1 = xs1 >> 7;
  const int c0 = ((xs0 & 127) ^ (((xs0 >> 7) & 7) << 4)) >> 1;
  const int c1 = ((xs1 & 127) ^ (((xs1 >> 7) & 7) << 4)) >> 1;
  const u16* Kb0 = Kp + ((bS + r0) << 10) + h * 64 + c0;
  const u16* Kb1 = Kp + ((bS + r1) << 10) + h * 64 + c1;
  const u16* Vb0 = VpT + (size_t)(h * 64 + r0) * 4096 + bS + c0;
  const u16* Vb1 = VpT + (size_t)(h * 64 + r1) * 4096 + bS + c1;

  bf16x8 aq0[2], aq1[2];
  {
    const u16* qp0 = Qp + ((bS + qt * 128 + wave * 32 + l15) << 10) + h * 64 + lq * 8;
    aq0[0] = *(const bf16x8*)(qp0);
    aq0[1] = *(const bf16x8*)(qp0 + 32);
    const u16* qp1 = qp0 + (16 << 10);
    aq1[0] = *(const bf16x8*)(qp1);
    aq1[1] = *(const bf16x8*)(qp1 + 32);
  }

  f32x4 o0[4], o1[4];
#pragma unroll
  for (int n = 0; n < 4; ++n) { o0[n] = (f32x4)0.0f; o1[n] = (f32x4)0.0f; }
  float m0 = -1e30f, m1 = -1e30f;
  float l0 = 0.f, l1 = 0.f;
  u16* Pw0 = Pl[wave][0];
  u16* Pw1 = Pl[wave][1];

  async16(Kb0, (char*)Kl[0] + xs0);
  async16(Kb1, (char*)Kl[0] + xs1);
  async16(Vb0, (char*)VTl[0] + xs0);
  async16(Vb1, (char*)VTl[0] + xs1);
  __syncthreads();

  int buf = 0;
  for (int t0 = 0; t0 < S_SZ; t0 += 64) {
    if (t0 + 64 < S_SZ) {
      const int tn = t0 + 64;
      async16(Kb0 + ((size_t)tn << 10), (char*)Kl[buf ^ 1] + xs0);
      async16(Kb1 + ((size_t)tn << 10), (char*)Kl[buf ^ 1] + xs1);
      async16(Vb0 + tn, (char*)VTl[buf ^ 1] + xs0);
      async16(Vb1 + tn, (char*)VTl[buf ^ 1] + xs1);
    }

    f32x4 s0[4], s1[4];
#pragma unroll
    for (int n = 0; n < 4; ++n) { s0[n] = (f32x4)0.0f; s1[n] = (f32x4)0.0f; }
    __builtin_amdgcn_s_setprio(1);
#pragma unroll
    for (int n = 0; n < 4; ++n)
#pragma unroll
      for (int kk = 0; kk < 2; ++kk) {
        int r = n * 16 + l15;
        int byte = ((r << 7) + kk * 64 + lq * 16) ^ ((r & 7) << 4);
        bf16x8 bk = *(const bf16x8*)((const char*)Kl[buf] + byte);
        s0[n] = mfma16(bk, aq0[kk], s0[n]);
        s1[n] = mfma16(bk, aq1[kk], s1[n]);
      }
    __builtin_amdgcn_s_setprio(0);

    {
      float mx = s0[0][0];
#pragma unroll
      for (int n = 0; n < 4; ++n)
#pragma unroll
        for (int j = 0; j < 4; ++j) mx = fmaxf(mx, s0[n][j]);
      mx = fmaxf(mx, __shfl_xor(mx, 16, 64));
      mx = fmaxf(mx, __shfl_xor(mx, 32, 64));
      if (__any(mx > m0 + 8.0f)) {
        float mn = fmaxf(m0, mx);
        float alpha = __expf(m0 - mn);
        m0 = mn;
        l0 *= alpha;
        float a0 = __shfl(alpha, lq * 4 + 0, 64);
        float a1 = __shfl(alpha, lq * 4 + 1, 64);
        float a2 = __shfl(alpha, lq * 4 + 2, 64);
        float a3 = __shfl(alpha, lq * 4 + 3, 64);
#pragma unroll
        for (int n = 0; n < 4; ++n) {
          o0[n][0] *= a0; o0[n][1] *= a1; o0[n][2] *= a2; o0[n][3] *= a3;
        }
      }
      float rs = 0.f;
#pragma unroll
      for (int n = 0; n < 4; ++n) {
        float p0 = __expf(s0[n][0] - m0);
        float p1 = __expf(s0[n][1] - m0);
        float p2 = __expf(s0[n][2] - m0);
        float p3 = __expf(s0[n][3] - m0);
        rs += (p0 + p1) + (p2 + p3);
        u32 lo = pack_bf16(p0, p1);
        u32 hi = pack_bf16(p2, p3);
        int byte = (l15 << 7) + (((n * 32 + lq * 8)) ^ ((l15 & 7) << 4));
        uint2 wv; wv.x = lo; wv.y = hi;
        *(uint2*)((char*)Pw0 + byte) = wv;
      }
      rs += __shfl_xor(rs, 16, 64);
      rs += __shfl_xor(rs, 32, 64);
      l0 += rs;
    }
    {
      float mx = s1[0][0];
#pragma unroll
      for (int n = 0; n < 4; ++n)
#pragma unroll
        for (int j = 0; j < 4; ++j) mx = fmaxf(mx, s1[n][j]);
      mx = fmaxf(mx, __shfl_xor(mx, 16, 64));
      mx = fmaxf(mx, __shfl_xor(mx, 32, 64));
      if (__any(mx > m1 + 8.0f)) {
        float mn = fmaxf(m1, mx);
        float alpha = __expf(m1 - mn);
        m1 = mn;
        l1 *= alpha;
        float a0 = __shfl(alpha, lq * 4 + 0, 64);
        float a1 = __shfl(alpha, lq * 4 + 1, 64);
        float a2 = __shfl(alpha, lq * 4 + 2, 64);
        float a3 = __shfl(alpha, lq * 4 + 3, 64);
#pragma unroll
        for (int n = 0; n < 4; ++n) {
          o1[n][0] *= a0; o1[n][1] *= a1; o1[n][2] *= a2; o1[n][3] *= a3;
        }
      }
      float rs = 0.f;
#pragma unroll
      for (int n = 0; n < 4; ++n) {
        float p0 = __expf(s1[n][0] - m1);
        float p1 = __expf(s1[n][1] - m1);
        float p2 = __expf(s1[n][2] - m1);
        float p3 = __expf(s1[n][3] - m1);
        rs += (p0 + p1) + (p2 + p3);
        u32 lo = pack_bf16(p0, p1);
        u32 hi = pack_bf16(p2, p3);
        int byte = (l15 << 7) + (((n * 32 + lq * 8)) ^ ((l15 & 7) << 4));
        uint2 wv; wv.x = lo; wv.y = hi;
        *(uint2*)((char*)Pw1 + byte) = wv;
      }
      rs += __shfl_xor(rs, 16, 64);
      rs += __shfl_xor(rs, 32, 64);
      l1 += rs;
    }

    __builtin_amdgcn_s_setprio(1);
#pragma unroll
    for (int kk = 0; kk < 2; ++kk) {
      int pbyte = (l15 << 7) + ((kk * 64 + lq * 16) ^ ((l15 & 7) << 4));
      bf16x8 pa0 = *(const bf16x8*)((const char*)Pw0 + pbyte);
      bf16x8 pa1 = *(const bf16x8*)((const char*)Pw1 + pbyte);
#pragma unroll
      for (int n = 0; n < 4; ++n) {
        int vr = n * 16 + l15;
        int byte = ((vr << 7) + kk * 64 + lq * 16) ^ ((vr & 7) << 4);
        bf16x8 bv = *(const bf16x8*)((const char*)VTl[buf] + byte);
        o0[n] = mfma16(pa0, bv, o0[n]);
        o1[n] = mfma16(pa1, bv, o1[n]);
      }
    }
    __builtin_amdgcn_s_setprio(0);

    __syncthreads();
    buf ^= 1;
  }

#pragma unroll
  for (int qg = 0; qg < 2; ++qg) {
    float lr = qg == 0 ? l0 : l1;
    f32x4* o = qg == 0 ? o0 : o1;
    float li0 = __shfl(lr, lq * 4 + 0, 64);
    float li1 = __shfl(lr, lq * 4 + 1, 64);
    float li2 = __shfl(lr, lq * 4 + 2, 64);
    float li3 = __shfl(lr, lq * 4 + 3, 64);
    float inv0 = 1.0f / li0, inv1 = 1.0f / li1, inv2 = 1.0f / li2, inv3 = 1.0f / li3;
#pragma unroll
    for (int n = 0; n < 4; ++n) {
      float vals[4] = {o[n][0] * inv0, o[n][1] * inv1, o[n][2] * inv2, o[n][3] * inv3};
#pragma unroll
      for (int j = 0; j < 4; ++j) {
        int row = qt * 128 + wave * 32 + qg * 16 + lq * 4 + j;
        int col = h * 64 + n * 16 + l15;
        Ow[((bS + row) << 10) + col] = f2bf(vals[j]);
      }
    }
  }
}

extern "C" void kernel_launch(void* const* d_in, const int* in_sizes, int n_in,
                              void* d_out, int out_size, void* d_ws, size_t ws_size,
                              hipStream_t stream) {
  const float* q  = (const float*)d_in[0];
  const float* k  = (const float*)d_in[1];
  const float* v  = (const float*)d_in[2];
  const float* Wq = (const float*)d_in[3];
  const float* bq = (const float*)d_in[4];
  const float* Wk = (const float*)d_in[5];
  const float* bk = (const float*)d_in[6];
  const float* Wv = (const float*)d_in[7];
  const float* bv = (const float*)d_in[8];
  const float* Wo = (const float*)d_in[9];
  const float* bo = (const float*)d_in[10];

  char* w = (char*)d_ws;
  const size_t MB = 1u << 20;
  u16* qb  = (u16*)(w + 0 * MB);
  u16* kb  = (u16*)(w + 8 * MB);
  u16* vb  = (u16*)(w + 16 * MB);
  u16* WqT = (u16*)(w + 24 * MB);
  u16* WkT = (u16*)(w + 26 * MB);
  u16* WvT = (u16*)(w + 28 * MB);
  u16* Wob = (u16*)(w + 30 * MB);
  u16* Qp  = (u16*)(w + 32 * MB);
  u16* Kp  = (u16*)(w + 40 * MB);
  u16* VpT = (u16*)(w + 48 * MB);
  u16* wvb = (u16*)(w + 56 * MB);

  prep<<<7424, 256, 0, stream>>>(q, k, v, Wo, Wq, Wk, Wv,
                                 qb, kb, vb, Wob, WqT, WkT, WvT);

  gemm3<<<192, 512, 0, stream>>>(qb, kb, vb, WqT, WkT, WvT, bq, bk, bv, Qp, Kp, VpT);

  attn<<<512, 256, 0, stream>>>(Qp, Kp, VpT, wvb);

  gemmO8<<<256, 512, 0, stream>>>(wvb, Wob, bo, (float*)d_out);
}

// Round 15
// 120.735 us; speedup vs baseline: 1.1893x; 1.0833x over previous
//
#include <hip/hip_runtime.h>

typedef unsigned short u16;
typedef unsigned int u32;
typedef __attribute__((ext_vector_type(8))) short bf16x8;
typedef __attribute__((ext_vector_type(4))) float f32x4;

#define B_SZ 4
#define S_SZ 1024
#define D_SZ 1024
#define H_SZ 16
#define E_SZ 64
#define M_SZ (B_SZ * S_SZ)   // 4096

__device__ __forceinline__ u16 f2bf(float f) {
  union { float f; unsigned u; } x; x.f = f;
  unsigned r = (x.u + 0x7FFFu + ((x.u >> 16) & 1u)) >> 16;
  return (u16)r;
}

__device__ __forceinline__ u32 pack_bf16(float lo, float hi) {
  return (u32)f2bf(lo) | ((u32)f2bf(hi) << 16);
}

__device__ __forceinline__ void async16(const void* g, void* l) {
  __builtin_amdgcn_global_load_lds(
      (const __attribute__((address_space(1))) void*)g,
      (__attribute__((address_space(3))) void*)l, 16, 0, 0);
}

__device__ __forceinline__ f32x4 mfma16(bf16x8 a, bf16x8 b, f32x4 c) {
  return __builtin_amdgcn_mfma_f32_16x16x32_bf16(a, b, c, 0, 0, 0);
}

// -------- merged prep: blocks [0,6656) cast q,k,v,Wo -> bf16; [6656,7424) transW --------
__global__ void prep(const float* __restrict__ q, const float* __restrict__ k,
                     const float* __restrict__ v, const float* __restrict__ Wo,
                     const float* __restrict__ Wq, const float* __restrict__ Wk,
                     const float* __restrict__ Wv,
                     u16* __restrict__ oq, u16* __restrict__ ok,
                     u16* __restrict__ ov, u16* __restrict__ oWo,
                     u16* __restrict__ Tq, u16* __restrict__ Tk, u16* __restrict__ Tv) {
  __shared__ float tile[64 * 68];
  const int tid = threadIdx.x;
  if (blockIdx.x < 6656) {
    // ---- cast part ----
    int gid = blockIdx.x * 256 + tid;
    const float* in;
    u16* out;
    int i;
    if (gid < (3 << 19)) {
      int sel = gid >> 19;
      i = (gid & ((1 << 19) - 1)) << 3;
      in = sel == 0 ? q : (sel == 1 ? k : v);
      out = sel == 0 ? oq : (sel == 1 ? ok : ov);
    } else {
      i = (gid - (3 << 19)) << 3;
      in = Wo;
      out = oWo;
    }
    float4 a = *(const float4*)(in + i);
    float4 b = *(const float4*)(in + i + 4);
    alignas(16) u16 r[8];
    r[0] = f2bf(a.x); r[1] = f2bf(a.y); r[2] = f2bf(a.z); r[3] = f2bf(a.w);
    r[4] = f2bf(b.x); r[5] = f2bf(b.y); r[6] = f2bf(b.z); r[7] = f2bf(b.w);
    *(uint4*)(out + i) = *(uint4*)r;
  } else {
    // ---- transW part ----
    const int blk = blockIdx.x - 6656;
    const int wsel = blk >> 8;
    const int bi = blk & 255;
    const float* W = wsel == 0 ? Wq : (wsel == 1 ? Wk : Wv);
    u16* WT = wsel == 0 ? Tq : (wsel == 1 ? Tk : Tv);
    const int h = bi >> 4;
    const int d0 = (bi & 15) << 6;
#pragma unroll
    for (int c = 0; c < 4; ++c) {
      const int dd = c * 16 + (tid >> 4);
      const int e4 = (tid & 15) << 2;
      float4 vq = *(const float4*)(W + (h << 16) + ((d0 + dd) << 6) + e4);
      *(float4*)(tile + dd * 68 + e4) = vq;
    }
    __syncthreads();
    {
      const int e = tid >> 2;
      const int dc = (tid & 3) << 4;
      alignas(16) u16 outv[16];
#pragma unroll
      for (int i = 0; i < 16; ++i) outv[i] = f2bf(tile[(dc + i) * 68 + e]);
      u16* dst = WT + (((size_t)(h << 6) + e) << 10) + d0 + dc;
      *(uint4*)(dst) = *(uint4*)outv;
      *(uint4*)(dst + 8) = *(uint4*)(outv + 8);
    }
  }
}

// ---------------- fused QKV projection GEMM (best measured: R7/R10/R12 form) ----------------
// 128x128 tile, BK=64, 4 waves, single-buffered, T1 XCD-chunked swizzle.
__global__ __launch_bounds__(256)
void gemm3(const u16* __restrict__ qb, const u16* __restrict__ kb, const u16* __restrict__ vb,
           const u16* __restrict__ Tq, const u16* __restrict__ Tk, const u16* __restrict__ Tv,
           const float* __restrict__ bq, const float* __restrict__ bk, const float* __restrict__ bv,
           u16* __restrict__ Qp, u16* __restrict__ Kp, u16* __restrict__ VpT) {
  __shared__ u16 Al[128 * 64];
  __shared__ u16 Bl[128 * 64];
  const int wg = blockIdx.x;
  const int swz = (wg & 7) * 96 + (wg >> 3);   // T1: bijective (768 % 8 == 0)
  const int g = swz >> 8;
  const int bi = swz & 255;
  const u16* A = g == 0 ? qb : (g == 1 ? kb : vb);
  const u16* BT = g == 0 ? Tq : (g == 1 ? Tk : Tv);
  const float* bias = g == 0 ? bq : (g == 1 ? bk : bv);
  u16* Cout = g == 0 ? Qp : (g == 1 ? Kp : VpT);
  const float scale = g == 0 ? 0.125f : 1.0f;

  const int tid = threadIdx.x;
  const int wave = tid >> 6;
  const int lane = tid & 63;
  const int l15 = lane & 15, lq = lane >> 4;
  const int bm = bi >> 3;
  const int bn = bi & 7;
  const int row0 = bm << 7, col0 = bn << 7;
  const int wr = ((wave >> 1) & 1) << 6;
  const int wc = (wave & 1) << 6;

  f32x4 acc[4][4];
#pragma unroll
  for (int m = 0; m < 4; ++m)
#pragma unroll
    for (int n = 0; n < 4; ++n) acc[m][n] = (f32x4)0.0f;

  for (int k0 = 0; k0 < 1024; k0 += 64) {
    __syncthreads();
#pragma unroll
    for (int c = 0; c < 4; ++c) {
      const int x = c * 4096 + tid * 16;
      const int gx = x ^ (((x >> 7) & 7) << 4);
      const int row = gx >> 7;
      const int cb = gx & 127;
      const u16* ga = A + (size_t)(row0 + row) * 1024 + k0 + (cb >> 1);
      const u16* gb = BT + (size_t)(col0 + row) * 1024 + k0 + (cb >> 1);
      async16(ga, (char*)Al + x);
      async16(gb, (char*)Bl + x);
    }
    __syncthreads();

    bf16x8 af[4][2], bfr[4][2];
#pragma unroll
    for (int m = 0; m < 4; ++m)
#pragma unroll
      for (int kf = 0; kf < 2; ++kf) {
        int r = wr + m * 16 + l15;
        int byte = ((r << 7) + kf * 64 + lq * 16) ^ ((r & 7) << 4);
        af[m][kf] = *(const bf16x8*)((const char*)Al + byte);
      }
#pragma unroll
    for (int n = 0; n < 4; ++n)
#pragma unroll
      for (int kf = 0; kf < 2; ++kf) {
        int r = wc + n * 16 + l15;
        int byte = ((r << 7) + kf * 64 + lq * 16) ^ ((r & 7) << 4);
        bfr[n][kf] = *(const bf16x8*)((const char*)Bl + byte);
      }
    if (g == 2) {
#pragma unroll
      for (int kf = 0; kf < 2; ++kf)
#pragma unroll
        for (int m = 0; m < 4; ++m)
#pragma unroll
          for (int n = 0; n < 4; ++n)
            acc[m][n] = mfma16(af[m][kf], bfr[n][kf], acc[m][n]);
    } else {
#pragma unroll
      for (int kf = 0; kf < 2; ++kf)
#pragma unroll
        for (int m = 0; m < 4; ++m)
#pragma unroll
          for (int n = 0; n < 4; ++n)
            acc[m][n] = mfma16(bfr[n][kf], af[m][kf], acc[m][n]);
    }
  }

  if (g == 2) {
#pragma unroll
    for (int m = 0; m < 4; ++m)
#pragma unroll
      for (int n = 0; n < 4; ++n) {
        int col = col0 + wc + n * 16 + l15;
        float bv = bias[col];
        int rowb = row0 + wr + m * 16 + lq * 4;
        alignas(8) u16 r4[4];
#pragma unroll
        for (int j = 0; j < 4; ++j) r4[j] = f2bf(acc[m][n][j] + bv);
        *(uint2*)(Cout + (size_t)col * 4096 + rowb) = *(uint2*)r4;
      }
  } else {
    float4 b4[4];
#pragma unroll
    for (int n = 0; n < 4; ++n)
      b4[n] = *(const float4*)(bias + col0 + wc + n * 16 + lq * 4);
#pragma unroll
    for (int m = 0; m < 4; ++m) {
      int row = row0 + wr + m * 16 + l15;
#pragma unroll
      for (int n = 0; n < 4; ++n) {
        int colbase = col0 + wc + n * 16 + lq * 4;
        u32 lo = pack_bf16((acc[m][n][0] + b4[n].x) * scale,
                           (acc[m][n][1] + b4[n].y) * scale);
        u32 hi = pack_bf16((acc[m][n][2] + b4[n].z) * scale,
                           (acc[m][n][3] + b4[n].w) * scale);
        uint2 wv; wv.x = lo; wv.y = hi;
        *(uint2*)(Cout + (size_t)row * 1024 + colbase) = wv;
      }
    }
  }
}

// ---------------- output GEMM: 8 waves + dbuf prefetch + T1 swizzle ----------------
__global__ __launch_bounds__(512, 4)
void gemmO8(const u16* __restrict__ A, const u16* __restrict__ BT,
            const float* __restrict__ bias, float* __restrict__ out) {
  __shared__ u16 Al[2][128 * 64];
  __shared__ u16 Bl[2][128 * 64];
  const int tid = threadIdx.x;
  const int wave = tid >> 6;
  const int lane = tid & 63;
  const int l15 = lane & 15, lq = lane >> 4;
  const int wg = blockIdx.x;
  const int bi = (wg & 7) * 32 + (wg >> 3);   // T1: bijective (256 % 8 == 0)
  const int bm = bi >> 3;
  const int bn = bi & 7;
  const int row0 = bm << 7, col0 = bn << 7;
  const int wr = (wave >> 1) << 5;
  const int wc = (wave & 1) << 6;

  int xs[2], rowS[2], cbS[2];
#pragma unroll
  for (int c = 0; c < 2; ++c) {
    int x = c * 8192 + tid * 16;
    int gx = x ^ (((x >> 7) & 7) << 4);
    xs[c] = x;
    rowS[c] = gx >> 7;
    cbS[c] = (gx & 127) >> 1;
  }

  f32x4 acc[2][4];
#pragma unroll
  for (int m = 0; m < 2; ++m)
#pragma unroll
    for (int n = 0; n < 4; ++n) acc[m][n] = (f32x4)0.0f;

#pragma unroll
  for (int c = 0; c < 2; ++c) {
    async16(A + (size_t)(row0 + rowS[c]) * 1024 + cbS[c], (char*)Al[0] + xs[c]);
    async16(BT + (size_t)(col0 + rowS[c]) * 1024 + cbS[c], (char*)Bl[0] + xs[c]);
  }
  __syncthreads();

  int buf = 0;
  for (int k0 = 0; k0 < 1024; k0 += 64) {
    if (k0 + 64 < 1024) {
      const int kn = k0 + 64;
#pragma unroll
      for (int c = 0; c < 2; ++c) {
        async16(A + (size_t)(row0 + rowS[c]) * 1024 + kn + cbS[c], (char*)Al[buf ^ 1] + xs[c]);
        async16(BT + (size_t)(col0 + rowS[c]) * 1024 + kn + cbS[c], (char*)Bl[buf ^ 1] + xs[c]);
      }
    }

    bf16x8 af[2][2], bfr[4][2];
#pragma unroll
    for (int m = 0; m < 2; ++m)
#pragma unroll
      for (int kf = 0; kf < 2; ++kf) {
        int r = wr + m * 16 + l15;
        int byte = ((r << 7) + kf * 64 + lq * 16) ^ ((r & 7) << 4);
        af[m][kf] = *(const bf16x8*)((const char*)Al[buf] + byte);
      }
#pragma unroll
    for (int n = 0; n < 4; ++n)
#pragma unroll
      for (int kf = 0; kf < 2; ++kf) {
        int r = wc + n * 16 + l15;
        int byte = ((r << 7) + kf * 64 + lq * 16) ^ ((r & 7) << 4);
        bfr[n][kf] = *(const bf16x8*)((const char*)Bl[buf] + byte);
      }
#pragma unroll
    for (int kf = 0; kf < 2; ++kf)
#pragma unroll
      for (int m = 0; m < 2; ++m)
#pragma unroll
        for (int n = 0; n < 4; ++n)
          acc[m][n] = mfma16(bfr[n][kf], af[m][kf], acc[m][n]);

    __syncthreads();
    buf ^= 1;
  }

  float4 b4[4];
#pragma unroll
  for (int n = 0; n < 4; ++n)
    b4[n] = *(const float4*)(bias + col0 + wc + n * 16 + lq * 4);
#pragma unroll
  for (int m = 0; m < 2; ++m) {
    int row = row0 + wr + m * 16 + l15;
#pragma unroll
    for (int n = 0; n < 4; ++n) {
      int colbase = col0 + wc + n * 16 + lq * 4;
      float4 v;
      v.x = acc[m][n][0] + b4[n].x;
      v.y = acc[m][n][1] + b4[n].y;
      v.z = acc[m][n][2] + b4[n].z;
      v.w = acc[m][n][3] + b4[n].w;
      *(float4*)(out + (size_t)row * 1024 + colbase) = v;
    }
  }
}

// ---------------- flash attention v4: QBLK=128, 32 q-rows/wave (2 q-groups) ----------------
__global__ __launch_bounds__(256)
void attn(const u16* __restrict__ Qp, const u16* __restrict__ Kp,
          const u16* __restrict__ VpT, u16* __restrict__ Ow) {
  __shared__ alignas(16) u16 Kl[2][64 * 64];
  __shared__ alignas(16) u16 VTl[2][64 * 64];
  __shared__ alignas(16) u16 Pl[4][2][16 * 64];
  const int tid = threadIdx.x;
  const int wave = tid >> 6;
  const int lane = tid & 63;
  const int l15 = lane & 15, lq = lane >> 4;
  const int wg = blockIdx.x;
  const int swz = (wg & 7) * 64 + (wg >> 3);  // T1: XCD k owns bh in [8k, 8k+8)
  const int qt = swz & 7;
  const int bh = swz >> 3;
  const int b = bh >> 4, h = bh & 15;
  const size_t bS = (size_t)b * S_SZ;

  const int xs0 = tid * 16, xs1 = 4096 + tid * 16;
  const int r0 = xs0 >> 7, r1 = xs1 >> 7;
  const int c0 = ((xs0 & 127) ^ (((xs0 >> 7) & 7) << 4)) >> 1;
  const int c1 = ((xs1 & 127) ^ (((xs1 >> 7) & 7) << 4)) >> 1;
  const u16* Kb0 = Kp + ((bS + r0) << 10) + h * 64 + c0;
  const u16* Kb1 = Kp + ((bS + r1) << 10) + h * 64 + c1;
  const u16* Vb0 = VpT + (size_t)(h * 64 + r0) * 4096 + bS + c0;
  const u16* Vb1 = VpT + (size_t)(h * 64 + r1) * 4096 + bS + c1;

  bf16x8 aq0[2], aq1[2];
  {
    const u16* qp0 = Qp + ((bS + qt * 128 + wave * 32 + l15) << 10) + h * 64 + lq * 8;
    aq0[0] = *(const bf16x8*)(qp0);
    aq0[1] = *(const bf16x8*)(qp0 + 32);
    const u16* qp1 = qp0 + (16 << 10);
    aq1[0] = *(const bf16x8*)(qp1);
    aq1[1] = *(const bf16x8*)(qp1 + 32);
  }

  f32x4 o0[4], o1[4];
#pragma unroll
  for (int n = 0; n < 4; ++n) { o0[n] = (f32x4)0.0f; o1[n] = (f32x4)0.0f; }
  float m0 = -1e30f, m1 = -1e30f;
  float l0 = 0.f, l1 = 0.f;
  u16* Pw0 = Pl[wave][0];
  u16* Pw1 = Pl[wave][1];

  async16(Kb0, (char*)Kl[0] + xs0);
  async16(Kb1, (char*)Kl[0] + xs1);
  async16(Vb0, (char*)VTl[0] + xs0);
  async16(Vb1, (char*)VTl[0] + xs1);
  __syncthreads();

  int buf = 0;
  for (int t0 = 0; t0 < S_SZ; t0 += 64) {
    if (t0 + 64 < S_SZ) {
      const int tn = t0 + 64;
      async16(Kb0 + ((size_t)tn << 10), (char*)Kl[buf ^ 1] + xs0);
      async16(Kb1 + ((size_t)tn << 10), (char*)Kl[buf ^ 1] + xs1);
      async16(Vb0 + tn, (char*)VTl[buf ^ 1] + xs0);
      async16(Vb1 + tn, (char*)VTl[buf ^ 1] + xs1);
    }

    f32x4 s0[4], s1[4];
#pragma unroll
    for (int n = 0; n < 4; ++n) { s0[n] = (f32x4)0.0f; s1[n] = (f32x4)0.0f; }
    __builtin_amdgcn_s_setprio(1);
#pragma unroll
    for (int n = 0; n < 4; ++n)
#pragma unroll
      for (int kk = 0; kk < 2; ++kk) {
        int r = n * 16 + l15;
        int byte = ((r << 7) + kk * 64 + lq * 16) ^ ((r & 7) << 4);
        bf16x8 bk = *(const bf16x8*)((const char*)Kl[buf] + byte);
        s0[n] = mfma16(bk, aq0[kk], s0[n]);
        s1[n] = mfma16(bk, aq1[kk], s1[n]);
      }
    __builtin_amdgcn_s_setprio(0);

    {
      float mx = s0[0][0];
#pragma unroll
      for (int n = 0; n < 4; ++n)
#pragma unroll
        for (int j = 0; j < 4; ++j) mx = fmaxf(mx, s0[n][j]);
      mx = fmaxf(mx, __shfl_xor(mx, 16, 64));
      mx = fmaxf(mx, __shfl_xor(mx, 32, 64));
      if (__any(mx > m0 + 8.0f)) {
        float mn = fmaxf(m0, mx);
        float alpha = __expf(m0 - mn);
        m0 = mn;
        l0 *= alpha;
        float a0 = __shfl(alpha, lq * 4 + 0, 64);
        float a1 = __shfl(alpha, lq * 4 + 1, 64);
        float a2 = __shfl(alpha, lq * 4 + 2, 64);
        float a3 = __shfl(alpha, lq * 4 + 3, 64);
#pragma unroll
        for (int n = 0; n < 4; ++n) {
          o0[n][0] *= a0; o0[n][1] *= a1; o0[n][2] *= a2; o0[n][3] *= a3;
        }
      }
      float rs = 0.f;
#pragma unroll
      for (int n = 0; n < 4; ++n) {
        float p0 = __expf(s0[n][0] - m0);
        float p1 = __expf(s0[n][1] - m0);
        float p2 = __expf(s0[n][2] - m0);
        float p3 = __expf(s0[n][3] - m0);
        rs += (p0 + p1) + (p2 + p3);
        u32 lo = pack_bf16(p0, p1);
        u32 hi = pack_bf16(p2, p3);
        int byte = (l15 << 7) + (((n * 32 + lq * 8)) ^ ((l15 & 7) << 4));
        uint2 wv; wv.x = lo; wv.y = hi;
        *(uint2*)((char*)Pw0 + byte) = wv;
      }
      rs += __shfl_xor(rs, 16, 64);
      rs += __shfl_xor(rs, 32, 64);
      l0 += rs;
    }
    {
      float mx = s1[0][0];
#pragma unroll
      for (int n = 0; n < 4; ++n)
#pragma unroll
        for (int j = 0; j < 4; ++j) mx = fmaxf(mx, s1[n][j]);
      mx = fmaxf(mx, __shfl_xor(mx, 16, 64));
      mx = fmaxf(mx, __shfl_xor(mx, 32, 64));
      if (__any(mx > m1 + 8.0f)) {
        float mn = fmaxf(m1, mx);
        float alpha = __expf(m1 - mn);
        m1 = mn;
        l1 *= alpha;
        float a0 = __shfl(alpha, lq * 4 + 0, 64);
        float a1 = __shfl(alpha, lq * 4 + 1, 64);
        float a2 = __shfl(alpha, lq * 4 + 2, 64);
        float a3 = __shfl(alpha, lq * 4 + 3, 64);
#pragma unroll
        for (int n = 0; n < 4; ++n) {
          o1[n][0] *= a0; o1[n][1] *= a1; o1[n][2] *= a2; o1[n][3] *= a3;
        }
      }
      float rs = 0.f;
#pragma unroll
      for (int n = 0; n < 4; ++n) {
        float p0 = __expf(s1[n][0] - m1);
        float p1 = __expf(s1[n][1] - m1);
        float p2 = __expf(s1[n][2] - m1);
        float p3 = __expf(s1[n][3] - m1);
        rs += (p0 + p1) + (p2 + p3);
        u32 lo = pack_bf16(p0, p1);
        u32 hi = pack_bf16(p2, p3);
        int byte = (l15 << 7) + (((n * 32 + lq * 8)) ^ ((l15 & 7) << 4));
        uint2 wv; wv.x = lo; wv.y = hi;
        *(uint2*)((char*)Pw1 + byte) = wv;
      }
      rs += __shfl_xor(rs, 16, 64);
      rs += __shfl_xor(rs, 32, 64);
      l1 += rs;
    }

    __builtin_amdgcn_s_setprio(1);
#pragma unroll
    for (int kk = 0; kk < 2; ++kk) {
      int pbyte = (l15 << 7) + ((kk * 64 + lq * 16) ^ ((l15 & 7) << 4));
      bf16x8 pa0 = *(const bf16x8*)((const char*)Pw0 + pbyte);
      bf16x8 pa1 = *(const bf16x8*)((const char*)Pw1 + pbyte);
#pragma unroll
      for (int n = 0; n < 4; ++n) {
        int vr = n * 16 + l15;
        int byte = ((vr << 7) + kk * 64 + lq * 16) ^ ((vr & 7) << 4);
        bf16x8 bv = *(const bf16x8*)((const char*)VTl[buf] + byte);
        o0[n] = mfma16(pa0, bv, o0[n]);
        o1[n] = mfma16(pa1, bv, o1[n]);
      }
    }
    __builtin_amdgcn_s_setprio(0);

    __syncthreads();
    buf ^= 1;
  }

#pragma unroll
  for (int qg = 0; qg < 2; ++qg) {
    float lr = qg == 0 ? l0 : l1;
    f32x4* o = qg == 0 ? o0 : o1;
    float li0 = __shfl(lr, lq * 4 + 0, 64);
    float li1 = __shfl(lr, lq * 4 + 1, 64);
    float li2 = __shfl(lr, lq * 4 + 2, 64);
    float li3 = __shfl(lr, lq * 4 + 3, 64);
    float inv0 = 1.0f / li0, inv1 = 1.0f / li1, inv2 = 1.0f / li2, inv3 = 1.0f / li3;
#pragma unroll
    for (int n = 0; n < 4; ++n) {
      float vals[4] = {o[n][0] * inv0, o[n][1] * inv1, o[n][2] * inv2, o[n][3] * inv3};
#pragma unroll
      for (int j = 0; j < 4; ++j) {
        int row = qt * 128 + wave * 32 + qg * 16 + lq * 4 + j;
        int col = h * 64 + n * 16 + l15;
        Ow[((bS + row) << 10) + col] = f2bf(vals[j]);
      }
    }
  }
}

extern "C" void kernel_launch(void* const* d_in, const int* in_sizes, int n_in,
                              void* d_out, int out_size, void* d_ws, size_t ws_size,
                              hipStream_t stream) {
  const float* q  = (const float*)d_in[0];
  const float* k  = (const float*)d_in[1];
  const float* v  = (const float*)d_in[2];
  const float* Wq = (const float*)d_in[3];
  const float* bq = (const float*)d_in[4];
  const float* Wk = (const float*)d_in[5];
  const float* bk = (const float*)d_in[6];
  const float* Wv = (const float*)d_in[7];
  const float* bv = (const float*)d_in[8];
  const float* Wo = (const float*)d_in[9];
  const float* bo = (const float*)d_in[10];

  char* w = (char*)d_ws;
  const size_t MB = 1u << 20;
  u16* qb  = (u16*)(w + 0 * MB);
  u16* kb  = (u16*)(w + 8 * MB);
  u16* vb  = (u16*)(w + 16 * MB);
  u16* WqT = (u16*)(w + 24 * MB);
  u16* WkT = (u16*)(w + 26 * MB);
  u16* WvT = (u16*)(w + 28 * MB);
  u16* Wob = (u16*)(w + 30 * MB);
  u16* Qp  = (u16*)(w + 32 * MB);
  u16* Kp  = (u16*)(w + 40 * MB);
  u16* VpT = (u16*)(w + 48 * MB);
  u16* wvb = (u16*)(w + 56 * MB);

  prep<<<7424, 256, 0, stream>>>(q, k, v, Wo, Wq, Wk, Wv,
                                 qb, kb, vb, Wob, WqT, WkT, WvT);

  gemm3<<<768, 256, 0, stream>>>(qb, kb, vb, WqT, WkT, WvT, bq, bk, bv, Qp, Kp, VpT);

  attn<<<512, 256, 0, stream>>>(Qp, Kp, VpT, wvb);

  gemmO8<<<256, 512, 0, stream>>>(wvb, Wob, bo, (float*)d_out);
}

// Round 17
// 120.346 us; speedup vs baseline: 1.1932x; 1.0032x over previous
//
#include <hip/hip_runtime.h>

typedef unsigned short u16;
typedef unsigned int u32;
typedef __attribute__((ext_vector_type(8))) short bf16x8;
typedef __attribute__((ext_vector_type(4))) float f32x4;

#define B_SZ 4
#define S_SZ 1024
#define D_SZ 1024
#define H_SZ 16
#define E_SZ 64
#define M_SZ (B_SZ * S_SZ)   // 4096

__device__ __forceinline__ u16 f2bf(float f) {
  union { float f; unsigned u; } x; x.f = f;
  unsigned r = (x.u + 0x7FFFu + ((x.u >> 16) & 1u)) >> 16;
  return (u16)r;
}

__device__ __forceinline__ u32 pack_bf16(float lo, float hi) {
  return (u32)f2bf(lo) | ((u32)f2bf(hi) << 16);
}

__device__ __forceinline__ void async16(const void* g, void* l) {
  __builtin_amdgcn_global_load_lds(
      (const __attribute__((address_space(1))) void*)g,
      (__attribute__((address_space(3))) void*)l, 16, 0, 0);
}

__device__ __forceinline__ f32x4 mfma16(bf16x8 a, bf16x8 b, f32x4 c) {
  return __builtin_amdgcn_mfma_f32_16x16x32_bf16(a, b, c, 0, 0, 0);
}

// -------- merged prep: blocks [0,6656) cast q,k,v,Wo -> bf16; [6656,7424) transW --------
__global__ void prep(const float* __restrict__ q, const float* __restrict__ k,
                     const float* __restrict__ v, const float* __restrict__ Wo,
                     const float* __restrict__ Wq, const float* __restrict__ Wk,
                     const float* __restrict__ Wv,
                     u16* __restrict__ oq, u16* __restrict__ ok,
                     u16* __restrict__ ov, u16* __restrict__ oWo,
                     u16* __restrict__ Tq, u16* __restrict__ Tk, u16* __restrict__ Tv) {
  __shared__ float tile[64 * 68];
  const int tid = threadIdx.x;
  if (blockIdx.x < 6656) {
    // ---- cast part ----
    int gid = blockIdx.x * 256 + tid;
    const float* in;
    u16* out;
    int i;
    if (gid < (3 << 19)) {
      int sel = gid >> 19;
      i = (gid & ((1 << 19) - 1)) << 3;
      in = sel == 0 ? q : (sel == 1 ? k : v);
      out = sel == 0 ? oq : (sel == 1 ? ok : ov);
    } else {
      i = (gid - (3 << 19)) << 3;
      in = Wo;
      out = oWo;
    }
    float4 a = *(const float4*)(in + i);
    float4 b = *(const float4*)(in + i + 4);
    alignas(16) u16 r[8];
    r[0] = f2bf(a.x); r[1] = f2bf(a.y); r[2] = f2bf(a.z); r[3] = f2bf(a.w);
    r[4] = f2bf(b.x); r[5] = f2bf(b.y); r[6] = f2bf(b.z); r[7] = f2bf(b.w);
    *(uint4*)(out + i) = *(uint4*)r;
  } else {
    // ---- transW part ----
    const int blk = blockIdx.x - 6656;
    const int wsel = blk >> 8;
    const int bi = blk & 255;
    const float* W = wsel == 0 ? Wq : (wsel == 1 ? Wk : Wv);
    u16* WT = wsel == 0 ? Tq : (wsel == 1 ? Tk : Tv);
    const int h = bi >> 4;
    const int d0 = (bi & 15) << 6;
#pragma unroll
    for (int c = 0; c < 4; ++c) {
      const int dd = c * 16 + (tid >> 4);
      const int e4 = (tid & 15) << 2;
      float4 vq = *(const float4*)(W + (h << 16) + ((d0 + dd) << 6) + e4);
      *(float4*)(tile + dd * 68 + e4) = vq;
    }
    __syncthreads();
    {
      const int e = tid >> 2;
      const int dc = (tid & 3) << 4;
      alignas(16) u16 outv[16];
#pragma unroll
      for (int i = 0; i < 16; ++i) outv[i] = f2bf(tile[(dc + i) * 68 + e]);
      u16* dst = WT + (((size_t)(h << 6) + e) << 10) + d0 + dc;
      *(uint4*)(dst) = *(uint4*)outv;
      *(uint4*)(dst + 8) = *(uint4*)(outv + 8);
    }
  }
}

// ---------------- fused QKV projection GEMM (best measured: R7/R10/R12 form) ----------------
// 128x128 tile, BK=64, 4 waves, single-buffered, T1 XCD-chunked swizzle.
__global__ __launch_bounds__(256)
void gemm3(const u16* __restrict__ qb, const u16* __restrict__ kb, const u16* __restrict__ vb,
           const u16* __restrict__ Tq, const u16* __restrict__ Tk, const u16* __restrict__ Tv,
           const float* __restrict__ bq, const float* __restrict__ bk, const float* __restrict__ bv,
           u16* __restrict__ Qp, u16* __restrict__ Kp, u16* __restrict__ VpT) {
  __shared__ u16 Al[128 * 64];
  __shared__ u16 Bl[128 * 64];
  const int wg = blockIdx.x;
  const int swz = (wg & 7) * 96 + (wg >> 3);   // T1: bijective (768 % 8 == 0)
  const int g = swz >> 8;
  const int bi = swz & 255;
  const u16* A = g == 0 ? qb : (g == 1 ? kb : vb);
  const u16* BT = g == 0 ? Tq : (g == 1 ? Tk : Tv);
  const float* bias = g == 0 ? bq : (g == 1 ? bk : bv);
  u16* Cout = g == 0 ? Qp : (g == 1 ? Kp : VpT);
  const float scale = g == 0 ? 0.125f : 1.0f;

  const int tid = threadIdx.x;
  const int wave = tid >> 6;
  const int lane = tid & 63;
  const int l15 = lane & 15, lq = lane >> 4;
  const int bm = bi >> 3;
  const int bn = bi & 7;
  const int row0 = bm << 7, col0 = bn << 7;
  const int wr = ((wave >> 1) & 1) << 6;
  const int wc = (wave & 1) << 6;

  f32x4 acc[4][4];
#pragma unroll
  for (int m = 0; m < 4; ++m)
#pragma unroll
    for (int n = 0; n < 4; ++n) acc[m][n] = (f32x4)0.0f;

  for (int k0 = 0; k0 < 1024; k0 += 64) {
    __syncthreads();
#pragma unroll
    for (int c = 0; c < 4; ++c) {
      const int x = c * 4096 + tid * 16;
      const int gx = x ^ (((x >> 7) & 7) << 4);
      const int row = gx >> 7;
      const int cb = gx & 127;
      const u16* ga = A + (size_t)(row0 + row) * 1024 + k0 + (cb >> 1);
      const u16* gb = BT + (size_t)(col0 + row) * 1024 + k0 + (cb >> 1);
      async16(ga, (char*)Al + x);
      async16(gb, (char*)Bl + x);
    }
    __syncthreads();

    bf16x8 af[4][2], bfr[4][2];
#pragma unroll
    for (int m = 0; m < 4; ++m)
#pragma unroll
      for (int kf = 0; kf < 2; ++kf) {
        int r = wr + m * 16 + l15;
        int byte = ((r << 7) + kf * 64 + lq * 16) ^ ((r & 7) << 4);
        af[m][kf] = *(const bf16x8*)((const char*)Al + byte);
      }
#pragma unroll
    for (int n = 0; n < 4; ++n)
#pragma unroll
      for (int kf = 0; kf < 2; ++kf) {
        int r = wc + n * 16 + l15;
        int byte = ((r << 7) + kf * 64 + lq * 16) ^ ((r & 7) << 4);
        bfr[n][kf] = *(const bf16x8*)((const char*)Bl + byte);
      }
    if (g == 2) {
#pragma unroll
      for (int kf = 0; kf < 2; ++kf)
#pragma unroll
        for (int m = 0; m < 4; ++m)
#pragma unroll
          for (int n = 0; n < 4; ++n)
            acc[m][n] = mfma16(af[m][kf], bfr[n][kf], acc[m][n]);
    } else {
#pragma unroll
      for (int kf = 0; kf < 2; ++kf)
#pragma unroll
        for (int m = 0; m < 4; ++m)
#pragma unroll
          for (int n = 0; n < 4; ++n)
            acc[m][n] = mfma16(bfr[n][kf], af[m][kf], acc[m][n]);
    }
  }

  if (g == 2) {
#pragma unroll
    for (int m = 0; m < 4; ++m)
#pragma unroll
      for (int n = 0; n < 4; ++n) {
        int col = col0 + wc + n * 16 + l15;
        float bv = bias[col];
        int rowb = row0 + wr + m * 16 + lq * 4;
        alignas(8) u16 r4[4];
#pragma unroll
        for (int j = 0; j < 4; ++j) r4[j] = f2bf(acc[m][n][j] + bv);
        *(uint2*)(Cout + (size_t)col * 4096 + rowb) = *(uint2*)r4;
      }
  } else {
    float4 b4[4];
#pragma unroll
    for (int n = 0; n < 4; ++n)
      b4[n] = *(const float4*)(bias + col0 + wc + n * 16 + lq * 4);
#pragma unroll
    for (int m = 0; m < 4; ++m) {
      int row = row0 + wr + m * 16 + l15;
#pragma unroll
      for (int n = 0; n < 4; ++n) {
        int colbase = col0 + wc + n * 16 + lq * 4;
        u32 lo = pack_bf16((acc[m][n][0] + b4[n].x) * scale,
                           (acc[m][n][1] + b4[n].y) * scale);
        u32 hi = pack_bf16((acc[m][n][2] + b4[n].z) * scale,
                           (acc[m][n][3] + b4[n].w) * scale);
        uint2 wv; wv.x = lo; wv.y = hi;
        *(uint2*)(Cout + (size_t)row * 1024 + colbase) = wv;
      }
    }
  }
}

// ---------------- output GEMM: 8 waves + dbuf prefetch + T1 swizzle ----------------
__global__ __launch_bounds__(512, 4)
void gemmO8(const u16* __restrict__ A, const u16* __restrict__ BT,
            const float* __restrict__ bias, float* __restrict__ out) {
  __shared__ u16 Al[2][128 * 64];
  __shared__ u16 Bl[2][128 * 64];
  const int tid = threadIdx.x;
  const int wave = tid >> 6;
  const int lane = tid & 63;
  const int l15 = lane & 15, lq = lane >> 4;
  const int wg = blockIdx.x;
  const int bi = (wg & 7) * 32 + (wg >> 3);   // T1: bijective (256 % 8 == 0)
  const int bm = bi >> 3;
  const int bn = bi & 7;
  const int row0 = bm << 7, col0 = bn << 7;
  const int wr = (wave >> 1) << 5;
  const int wc = (wave & 1) << 6;

  int xs[2], rowS[2], cbS[2];
#pragma unroll
  for (int c = 0; c < 2; ++c) {
    int x = c * 8192 + tid * 16;
    int gx = x ^ (((x >> 7) & 7) << 4);
    xs[c] = x;
    rowS[c] = gx >> 7;
    cbS[c] = (gx & 127) >> 1;
  }

  f32x4 acc[2][4];
#pragma unroll
  for (int m = 0; m < 2; ++m)
#pragma unroll
    for (int n = 0; n < 4; ++n) acc[m][n] = (f32x4)0.0f;

#pragma unroll
  for (int c = 0; c < 2; ++c) {
    async16(A + (size_t)(row0 + rowS[c]) * 1024 + cbS[c], (char*)Al[0] + xs[c]);
    async16(BT + (size_t)(col0 + rowS[c]) * 1024 + cbS[c], (char*)Bl[0] + xs[c]);
  }
  __syncthreads();

  int buf = 0;
  for (int k0 = 0; k0 < 1024; k0 += 64) {
    if (k0 + 64 < 1024) {
      const int kn = k0 + 64;
#pragma unroll
      for (int c = 0; c < 2; ++c) {
        async16(A + (size_t)(row0 + rowS[c]) * 1024 + kn + cbS[c], (char*)Al[buf ^ 1] + xs[c]);
        async16(BT + (size_t)(col0 + rowS[c]) * 1024 + kn + cbS[c], (char*)Bl[buf ^ 1] + xs[c]);
      }
    }

    bf16x8 af[2][2], bfr[4][2];
#pragma unroll
    for (int m = 0; m < 2; ++m)
#pragma unroll
      for (int kf = 0; kf < 2; ++kf) {
        int r = wr + m * 16 + l15;
        int byte = ((r << 7) + kf * 64 + lq * 16) ^ ((r & 7) << 4);
        af[m][kf] = *(const bf16x8*)((const char*)Al[buf] + byte);
      }
#pragma unroll
    for (int n = 0; n < 4; ++n)
#pragma unroll
      for (int kf = 0; kf < 2; ++kf) {
        int r = wc + n * 16 + l15;
        int byte = ((r << 7) + kf * 64 + lq * 16) ^ ((r & 7) << 4);
        bfr[n][kf] = *(const bf16x8*)((const char*)Bl[buf] + byte);
      }
#pragma unroll
    for (int kf = 0; kf < 2; ++kf)
#pragma unroll
      for (int m = 0; m < 2; ++m)
#pragma unroll
        for (int n = 0; n < 4; ++n)
          acc[m][n] = mfma16(bfr[n][kf], af[m][kf], acc[m][n]);

    __syncthreads();
    buf ^= 1;
  }

  float4 b4[4];
#pragma unroll
  for (int n = 0; n < 4; ++n)
    b4[n] = *(const float4*)(bias + col0 + wc + n * 16 + lq * 4);
#pragma unroll
  for (int m = 0; m < 2; ++m) {
    int row = row0 + wr + m * 16 + l15;
#pragma unroll
    for (int n = 0; n < 4; ++n) {
      int colbase = col0 + wc + n * 16 + lq * 4;
      float4 v;
      v.x = acc[m][n][0] + b4[n].x;
      v.y = acc[m][n][1] + b4[n].y;
      v.z = acc[m][n][2] + b4[n].z;
      v.w = acc[m][n][3] + b4[n].w;
      *(float4*)(out + (size_t)row * 1024 + colbase) = v;
    }
  }
}

// ---------------- flash attention v4: QBLK=128, 32 q-rows/wave (2 q-groups) ----------------
__global__ __launch_bounds__(256)
void attn(const u16* __restrict__ Qp, const u16* __restrict__ Kp,
          const u16* __restrict__ VpT, u16* __restrict__ Ow) {
  __shared__ alignas(16) u16 Kl[2][64 * 64];
  __shared__ alignas(16) u16 VTl[2][64 * 64];
  __shared__ alignas(16) u16 Pl[4][2][16 * 64];
  const int tid = threadIdx.x;
  const int wave = tid >> 6;
  const int lane = tid & 63;
  const int l15 = lane & 15, lq = lane >> 4;
  const int wg = blockIdx.x;
  const int swz = (wg & 7) * 64 + (wg >> 3);  // T1: XCD k owns bh in [8k, 8k+8)
  const int qt = swz & 7;
  const int bh = swz >> 3;
  const int b = bh >> 4, h = bh & 15;
  const size_t bS = (size_t)b * S_SZ;

  const int xs0 = tid * 16, xs1 = 4096 + tid * 16;
  const int r0 = xs0 >> 7, r1 = xs1 >> 7;
  const int c0 = ((xs0 & 127) ^ (((xs0 >> 7) & 7) << 4)) >> 1;
  const int c1 = ((xs1 & 127) ^ (((xs1 >> 7) & 7) << 4)) >> 1;
  const u16* Kb0 = Kp + ((bS + r0) << 10) + h * 64 + c0;
  const u16* Kb1 = Kp + ((bS + r1) << 10) + h * 64 + c1;
  const u16* Vb0 = VpT + (size_t)(h * 64 + r0) * 4096 + bS + c0;
  const u16* Vb1 = VpT + (size_t)(h * 64 + r1) * 4096 + bS + c1;

  bf16x8 aq0[2], aq1[2];
  {
    const u16* qp0 = Qp + ((bS + qt * 128 + wave * 32 + l15) << 10) + h * 64 + lq * 8;
    aq0[0] = *(const bf16x8*)(qp0);
    aq0[1] = *(const bf16x8*)(qp0 + 32);
    const u16* qp1 = qp0 + (16 << 10);
    aq1[0] = *(const bf16x8*)(qp1);
    aq1[1] = *(const bf16x8*)(qp1 + 32);
  }

  f32x4 o0[4], o1[4];
#pragma unroll
  for (int n = 0; n < 4; ++n) { o0[n] = (f32x4)0.0f; o1[n] = (f32x4)0.0f; }
  float m0 = -1e30f, m1 = -1e30f;
  float l0 = 0.f, l1 = 0.f;
  u16* Pw0 = Pl[wave][0];
  u16* Pw1 = Pl[wave][1];

  async16(Kb0, (char*)Kl[0] + xs0);
  async16(Kb1, (char*)Kl[0] + xs1);
  async16(Vb0, (char*)VTl[0] + xs0);
  async16(Vb1, (char*)VTl[0] + xs1);
  __syncthreads();

  int buf = 0;
  for (int t0 = 0; t0 < S_SZ; t0 += 64) {
    if (t0 + 64 < S_SZ) {
      const int tn = t0 + 64;
      async16(Kb0 + ((size_t)tn << 10), (char*)Kl[buf ^ 1] + xs0);
      async16(Kb1 + ((size_t)tn << 10), (char*)Kl[buf ^ 1] + xs1);
      async16(Vb0 + tn, (char*)VTl[buf ^ 1] + xs0);
      async16(Vb1 + tn, (char*)VTl[buf ^ 1] + xs1);
    }

    f32x4 s0[4], s1[4];
#pragma unroll
    for (int n = 0; n < 4; ++n) { s0[n] = (f32x4)0.0f; s1[n] = (f32x4)0.0f; }
    __builtin_amdgcn_s_setprio(1);
#pragma unroll
    for (int n = 0; n < 4; ++n)
#pragma unroll
      for (int kk = 0; kk < 2; ++kk) {
        int r = n * 16 + l15;
        int byte = ((r << 7) + kk * 64 + lq * 16) ^ ((r & 7) << 4);
        bf16x8 bk = *(const bf16x8*)((const char*)Kl[buf] + byte);
        s0[n] = mfma16(bk, aq0[kk], s0[n]);
        s1[n] = mfma16(bk, aq1[kk], s1[n]);
      }
    __builtin_amdgcn_s_setprio(0);

    {
      float mx = s0[0][0];
#pragma unroll
      for (int n = 0; n < 4; ++n)
#pragma unroll
        for (int j = 0; j < 4; ++j) mx = fmaxf(mx, s0[n][j]);
      mx = fmaxf(mx, __shfl_xor(mx, 16, 64));
      mx = fmaxf(mx, __shfl_xor(mx, 32, 64));
      if (__any(mx > m0 + 8.0f)) {
        float mn = fmaxf(m0, mx);
        float alpha = __expf(m0 - mn);
        m0 = mn;
        l0 *= alpha;
        float a0 = __shfl(alpha, lq * 4 + 0, 64);
        float a1 = __shfl(alpha, lq * 4 + 1, 64);
        float a2 = __shfl(alpha, lq * 4 + 2, 64);
        float a3 = __shfl(alpha, lq * 4 + 3, 64);
#pragma unroll
        for (int n = 0; n < 4; ++n) {
          o0[n][0] *= a0; o0[n][1] *= a1; o0[n][2] *= a2; o0[n][3] *= a3;
        }
      }
      float rs = 0.f;
#pragma unroll
      for (int n = 0; n < 4; ++n) {
        float p0 = __expf(s0[n][0] - m0);
        float p1 = __expf(s0[n][1] - m0);
        float p2 = __expf(s0[n][2] - m0);
        float p3 = __expf(s0[n][3] - m0);
        rs += (p0 + p1) + (p2 + p3);
        u32 lo = pack_bf16(p0, p1);
        u32 hi = pack_bf16(p2, p3);
        int byte = (l15 << 7) + (((n * 32 + lq * 8)) ^ ((l15 & 7) << 4));
        uint2 wv; wv.x = lo; wv.y = hi;
        *(uint2*)((char*)Pw0 + byte) = wv;
      }
      rs += __shfl_xor(rs, 16, 64);
      rs += __shfl_xor(rs, 32, 64);
      l0 += rs;
    }
    {
      float mx = s1[0][0];
#pragma unroll
      for (int n = 0; n < 4; ++n)
#pragma unroll
        for (int j = 0; j < 4; ++j) mx = fmaxf(mx, s1[n][j]);
      mx = fmaxf(mx, __shfl_xor(mx, 16, 64));
      mx = fmaxf(mx, __shfl_xor(mx, 32, 64));
      if (__any(mx > m1 + 8.0f)) {
        float mn = fmaxf(m1, mx);
        float alpha = __expf(m1 - mn);
        m1 = mn;
        l1 *= alpha;
        float a0 = __shfl(alpha, lq * 4 + 0, 64);
        float a1 = __shfl(alpha, lq * 4 + 1, 64);
        float a2 = __shfl(alpha, lq * 4 + 2, 64);
        float a3 = __shfl(alpha, lq * 4 + 3, 64);
#pragma unroll
        for (int n = 0; n < 4; ++n) {
          o1[n][0] *= a0; o1[n][1] *= a1; o1[n][2] *= a2; o1[n][3] *= a3;
        }
      }
      float rs = 0.f;
#pragma unroll
      for (int n = 0; n < 4; ++n) {
        float p0 = __expf(s1[n][0] - m1);
        float p1 = __expf(s1[n][1] - m1);
        float p2 = __expf(s1[n][2] - m1);
        float p3 = __expf(s1[n][3] - m1);
        rs += (p0 + p1) + (p2 + p3);
        u32 lo = pack_bf16(p0, p1);
        u32 hi = pack_bf16(p2, p3);
        int byte = (l15 << 7) + (((n * 32 + lq * 8)) ^ ((l15 & 7) << 4));
        uint2 wv; wv.x = lo; wv.y = hi;
        *(uint2*)((char*)Pw1 + byte) = wv;
      }
      rs += __shfl_xor(rs, 16, 64);
      rs += __shfl_xor(rs, 32, 64);
      l1 += rs;
    }

    __builtin_amdgcn_s_setprio(1);
#pragma unroll
    for (int kk = 0; kk < 2; ++kk) {
      int pbyte = (l15 << 7) + ((kk * 64 + lq * 16) ^ ((l15 & 7) << 4));
      bf16x8 pa0 = *(const bf16x8*)((const char*)Pw0 + pbyte);
      bf16x8 pa1 = *(const bf16x8*)((const char*)Pw1 + pbyte);
#pragma unroll
      for (int n = 0; n < 4; ++n) {
        int vr = n * 16 + l15;
        int byte = ((vr << 7) + kk * 64 + lq * 16) ^ ((vr & 7) << 4);
        bf16x8 bv = *(const bf16x8*)((const char*)VTl[buf] + byte);
        o0[n] = mfma16(pa0, bv, o0[n]);
        o1[n] = mfma16(pa1, bv, o1[n]);
      }
    }
    __builtin_amdgcn_s_setprio(0);

    __syncthreads();
    buf ^= 1;
  }

#pragma unroll
  for (int qg = 0; qg < 2; ++qg) {
    float lr = qg == 0 ? l0 : l1;
    f32x4* o = qg == 0 ? o0 : o1;
    float li0 = __shfl(lr, lq * 4 + 0, 64);
    float li1 = __shfl(lr, lq * 4 + 1, 64);
    float li2 = __shfl(lr, lq * 4 + 2, 64);
    float li3 = __shfl(lr, lq * 4 + 3, 64);
    float inv0 = 1.0f / li0, inv1 = 1.0f / li1, inv2 = 1.0f / li2, inv3 = 1.0f / li3;
#pragma unroll
    for (int n = 0; n < 4; ++n) {
      float vals[4] = {o[n][0] * inv0, o[n][1] * inv1, o[n][2] * inv2, o[n][3] * inv3};
#pragma unroll
      for (int j = 0; j < 4; ++j) {
        int row = qt * 128 + wave * 32 + qg * 16 + lq * 4 + j;
        int col = h * 64 + n * 16 + l15;
        Ow[((bS + row) << 10) + col] = f2bf(vals[j]);
      }
    }
  }
}

extern "C" void kernel_launch(void* const* d_in, const int* in_sizes, int n_in,
                              void* d_out, int out_size, void* d_ws, size_t ws_size,
                              hipStream_t stream) {
  const float* q  = (const float*)d_in[0];
  const float* k  = (const float*)d_in[1];
  const float* v  = (const float*)d_in[2];
  const float* Wq = (const float*)d_in[3];
  const float* bq = (const float*)d_in[4];
  const float* Wk = (const float*)d_in[5];
  const float* bk = (const float*)d_in[6];
  const float* Wv = (const float*)d_in[7];
  const float* bv = (const float*)d_in[8];
  const float* Wo = (const float*)d_in[9];
  const float* bo = (const float*)d_in[10];

  char* w = (char*)d_ws;
  const size_t MB = 1u << 20;
  u16* qb  = (u16*)(w + 0 * MB);
  u16* kb  = (u16*)(w + 8 * MB);
  u16* vb  = (u16*)(w + 16 * MB);
  u16* WqT = (u16*)(w + 24 * MB);
  u16* WkT = (u16*)(w + 26 * MB);
  u16* WvT = (u16*)(w + 28 * MB);
  u16* Wob = (u16*)(w + 30 * MB);
  u16* Qp  = (u16*)(w + 32 * MB);
  u16* Kp  = (u16*)(w + 40 * MB);
  u16* VpT = (u16*)(w + 48 * MB);
  u16* wvb = (u16*)(w + 56 * MB);

  prep<<<7424, 256, 0, stream>>>(q, k, v, Wo, Wq, Wk, Wv,
                                 qb, kb, vb, Wob, WqT, WkT, WvT);

  gemm3<<<768, 256, 0, stream>>>(qb, kb, vb, WqT, WkT, WvT, bq, bk, bv, Qp, Kp, VpT);

  attn<<<512, 256, 0, stream>>>(Qp, Kp, VpT, wvb);

  gemmO8<<<256, 512, 0, stream>>>(wvb, Wob, bo, (float*)d_out);
}